// Round 1
// baseline (3369.006 us; speedup 1.0000x reference)
//
#include <hip/hip_runtime.h>
#include <math.h>

#define BB 2
#define LL 768
#define CC 256
#define CZ 64
#define NH 8
#define NBLK 4
#define HD 32
#define BL (BB*LL)   // 1536

__device__ __forceinline__ float gelu_exact(float x) {
    return 0.5f * x * (1.0f + erff(x * 0.70710678118654752f));
}

// ---------------- time embedding + MLP -> time_cond (B,256) ----------------
__global__ __launch_bounds__(256) void k_time(
        const float* __restrict__ t,
        const float* __restrict__ tw1, const float* __restrict__ tb1,
        const float* __restrict__ tw2, const float* __restrict__ tb2,
        float* __restrict__ time_cond) {
    __shared__ float temb[256];
    __shared__ float mid[1024];
    int b = blockIdx.x;
    int tid = threadIdx.x;
    if (tid < 128) {
        float f = expf(-logf(10000.0f) * (float)tid / 128.0f);
        float a = t[b] * f;
        temb[tid]       = cosf(a);
        temb[128 + tid] = sinf(a);
    }
    __syncthreads();
    // mid = gelu(temb @ tw1 + tb1): 1024 outputs, 4 per thread
    #pragma unroll
    for (int m = 0; m < 4; ++m) {
        int col = tid + 256 * m;
        float acc = tb1[col];
        #pragma unroll 8
        for (int k = 0; k < 256; ++k) acc += temb[k] * tw1[(size_t)k * 1024 + col];
        mid[col] = gelu_exact(acc);
    }
    __syncthreads();
    float acc = tb2[tid];
    #pragma unroll 8
    for (int k = 0; k < 1024; ++k) acc += mid[k] * tw2[(size_t)k * 256 + tid];
    time_cond[b * 256 + tid] = acc;
}

// ---------------- adaln scale/shift tables: ss = time_cond @ apw + apb ------
// grid (NBLK, B, 2), 512 threads
__global__ __launch_bounds__(512) void k_ss(
        const float* __restrict__ tc,
        const float* __restrict__ apw1, const float* __restrict__ apb1,
        const float* __restrict__ apw2, const float* __restrict__ apb2,
        float* __restrict__ ss1, float* __restrict__ ss2) {
    int n = blockIdx.x, b = blockIdx.y, which = blockIdx.z;
    const float* apw = which ? apw2 : apw1;
    const float* apb = which ? apb2 : apb1;
    float* ss = which ? ss2 : ss1;
    __shared__ float tcl[256];
    int tid = threadIdx.x;
    if (tid < 256) tcl[tid] = tc[b * 256 + tid];
    __syncthreads();
    float acc = apb[n * 512 + tid];
    const float* w = apw + (size_t)n * 256 * 512 + tid;
    #pragma unroll 8
    for (int k = 0; k < 256; ++k) acc += tcl[k] * w[(size_t)k * 512];
    ss[(size_t)(n * BB + b) * 512 + tid] = acc;
}

// ---------------- h init ----------------------------------------------------
__global__ __launch_bounds__(256) void k_init_h(
        const float* __restrict__ rots, const float* __restrict__ trans,
        const float* __restrict__ single,
        const float* __restrict__ frame_w, const float* __restrict__ frame_b,
        const float* __restrict__ single_w, const float* __restrict__ single_b,
        float* __restrict__ h) {
    int row = blockIdx.x;
    int tid = threadIdx.x;
    __shared__ float ff[12];
    __shared__ float sr[256];
    if (tid < 9) ff[tid] = rots[(size_t)row * 9 + tid];
    else if (tid < 12) ff[tid] = trans[(size_t)row * 3 + (tid - 9)];
    sr[tid] = single[(size_t)row * 256 + tid];
    __syncthreads();
    float acc = frame_b[tid] + single_b[tid];
    #pragma unroll
    for (int k = 0; k < 12; ++k) acc += ff[k] * frame_w[k * 256 + tid];
    #pragma unroll 8
    for (int k = 0; k < 256; ++k) acc += sr[k] * single_w[k * 256 + tid];
    h[(size_t)row * 256 + tid] = acc;
}

// ---------------- adaln layernorm ------------------------------------------
// g/beta pre-offset by n*256; ss pre-offset by n*B*512
__global__ __launch_bounds__(256) void k_adaln(
        const float* __restrict__ h, const float* __restrict__ g,
        const float* __restrict__ beta, const float* __restrict__ ss,
        float* __restrict__ out) {
    int row = blockIdx.x;
    int b = row / LL;
    int tid = threadIdx.x;
    float x = h[(size_t)row * 256 + tid];
    float s = x, sq = x * x;
    #pragma unroll
    for (int off = 32; off > 0; off >>= 1) {
        s  += __shfl_down(s,  off, 64);
        sq += __shfl_down(sq, off, 64);
    }
    __shared__ float red[8];
    int wave = tid >> 6, lane = tid & 63;
    if (lane == 0) { red[wave] = s; red[4 + wave] = sq; }
    __syncthreads();
    if (tid == 0) {
        float ts = red[0] + red[1] + red[2] + red[3];
        float tq = red[4] + red[5] + red[6] + red[7];
        float mu = ts * (1.0f / 256.0f);
        float var = tq * (1.0f / 256.0f) - mu * mu;
        red[0] = mu;
        red[1] = rsqrtf(var + 1e-5f);
    }
    __syncthreads();
    float mu = red[0], inv = red[1];
    float ln = (x - mu) * inv * g[tid] + beta[tid];
    float scale = ss[b * 512 + tid];
    float shift = ss[b * 512 + 256 + tid];
    out[(size_t)row * 256 + tid] = ln * (1.0f + scale) + shift;
}

// ---------------- generic tiled GEMM: 4 rows/block, 256 threads ------------
// C[M,N] = A[M,K] @ W[K,N] (+bias)(gelu)(+resid). N=256*NCOL, K=256*KCH.
template<int NCOL, int KCH>
__global__ __launch_bounds__(256) void k_gemm4(
        const float* __restrict__ A, const float* __restrict__ W,
        const float* __restrict__ bias, const float* __restrict__ resid,
        float* __restrict__ out, int flags) {
    const int N = 256 * NCOL;
    const int K = 256 * KCH;
    int row0 = blockIdx.x * 4;
    int tid = threadIdx.x;
    __shared__ float a_s[4][256];
    float acc[4][NCOL];
    #pragma unroll
    for (int r = 0; r < 4; ++r)
        #pragma unroll
        for (int m = 0; m < NCOL; ++m) acc[r][m] = 0.f;

    for (int kc = 0; kc < KCH; ++kc) {
        if (kc) __syncthreads();
        {
            int r = tid >> 6, c4 = tid & 63;
            float4 av = reinterpret_cast<const float4*>(
                A + (size_t)(row0 + r) * K + kc * 256)[c4];
            *reinterpret_cast<float4*>(&a_s[r][c4 * 4]) = av;
        }
        __syncthreads();
        const float* Wp = W + (size_t)kc * 256 * N + tid;
        #pragma unroll 4
        for (int k = 0; k < 256; ++k) {
            float bv[NCOL];
            #pragma unroll
            for (int m = 0; m < NCOL; ++m) bv[m] = Wp[(size_t)k * N + 256 * m];
            #pragma unroll
            for (int r = 0; r < 4; ++r) {
                float a = a_s[r][k];
                #pragma unroll
                for (int m = 0; m < NCOL; ++m) acc[r][m] += a * bv[m];
            }
        }
    }
    #pragma unroll
    for (int r = 0; r < 4; ++r) {
        int row = row0 + r;
        #pragma unroll
        for (int m = 0; m < NCOL; ++m) {
            int col = tid + 256 * m;
            float v = acc[r][m];
            if (flags & 1) v += bias[col];
            if (flags & 2) v = gelu_exact(v);
            if (flags & 4) v += resid[(size_t)row * N + col];
            out[(size_t)row * N + col] = v;
        }
    }
}

// ---------------- fused attention: one block per (b,i) ----------------------
// pw pre-offset by n*CZ*NH
__global__ __launch_bounds__(256) void k_attn(
        const float* __restrict__ q, const float* __restrict__ kk,
        const float* __restrict__ v, const float* __restrict__ pair,
        const float* __restrict__ pw, float* __restrict__ outp) {
    int blk = blockIdx.x;
    int b = blk / LL, i = blk % LL;
    int tid = threadIdx.x;
    __shared__ float q_s[256];
    __shared__ float pw_s[CZ * NH];     // 512
    __shared__ float lg[NH][LL];        // 6144 floats
    __shared__ float part[8][256];
    __shared__ float invs[NH];
    size_t rowq = (size_t)(b * LL + i) * 256;
    q_s[tid] = q[rowq + tid];
    pw_s[tid] = pw[tid];
    pw_s[tid + 256] = pw[tid + 256];
    __syncthreads();

    const float scale = 0.17677669529663687f; // 1/sqrt(32)
    for (int j = tid; j < LL; j += 256) {
        const float4* k4 = reinterpret_cast<const float4*>(kk + (size_t)(b * LL + j) * 256);
        const float4* q4 = reinterpret_cast<const float4*>(q_s);
        float dot[NH];
        #pragma unroll
        for (int h = 0; h < NH; ++h) {
            float sx = 0.f, sy = 0.f, sz = 0.f, sw = 0.f;
            #pragma unroll
            for (int dd = 0; dd < 8; ++dd) {
                float4 kv = k4[h * 8 + dd];
                float4 qv = q4[h * 8 + dd];
                sx += qv.x * kv.x; sy += qv.y * kv.y;
                sz += qv.z * kv.z; sw += qv.w * kv.w;
            }
            dot[h] = (sx + sy) + (sz + sw);
        }
        const float4* p4 = reinterpret_cast<const float4*>(
            pair + ((size_t)(b * LL + i) * LL + j) * CZ);
        float bias[NH];
        #pragma unroll
        for (int h = 0; h < NH; ++h) bias[h] = 0.f;
        #pragma unroll
        for (int c4 = 0; c4 < 16; ++c4) {
            float4 pv = p4[c4];
            int c = c4 * 4;
            #pragma unroll
            for (int h = 0; h < NH; ++h)
                bias[h] += pv.x * pw_s[(c + 0) * NH + h] + pv.y * pw_s[(c + 1) * NH + h]
                         + pv.z * pw_s[(c + 2) * NH + h] + pv.w * pw_s[(c + 3) * NH + h];
        }
        #pragma unroll
        for (int h = 0; h < NH; ++h) lg[h][j] = dot[h] * scale + bias[h];
    }
    __syncthreads();

    int wave = tid >> 6, lane = tid & 63;
    for (int h = wave; h < NH; h += 4) {
        float mx = -1e30f;
        for (int j = lane; j < LL; j += 64) mx = fmaxf(mx, lg[h][j]);
        #pragma unroll
        for (int off = 32; off > 0; off >>= 1) mx = fmaxf(mx, __shfl_xor(mx, off, 64));
        float sm = 0.f;
        for (int j = lane; j < LL; j += 64) {
            float e = __expf(lg[h][j] - mx);
            lg[h][j] = e;
            sm += e;
        }
        #pragma unroll
        for (int off = 32; off > 0; off >>= 1) sm += __shfl_xor(sm, off, 64);
        if (lane == 0) invs[h] = 1.0f / sm;
    }
    __syncthreads();

    int g = tid >> 5, d = tid & 31;
    float acc[NH];
    #pragma unroll
    for (int h = 0; h < NH; ++h) acc[h] = 0.f;
    for (int j = g; j < LL; j += 8) {
        const float* vr = v + (size_t)(b * LL + j) * 256;
        #pragma unroll
        for (int h = 0; h < NH; ++h) acc[h] += lg[h][j] * vr[h * 32 + d];
    }
    #pragma unroll
    for (int h = 0; h < NH; ++h) part[g][h * 32 + d] = acc[h];
    __syncthreads();
    float sum = 0.f;
    #pragma unroll
    for (int g2 = 0; g2 < 8; ++g2) sum += part[g2][tid];
    outp[rowq + tid] = sum * invs[tid >> 5];
}

// ---------------- final frame update ---------------------------------------
__global__ __launch_bounds__(256) void k_final(
        const float* __restrict__ h, const float* __restrict__ out_w,
        const float* __restrict__ out_b, const float* __restrict__ rots,
        const float* __restrict__ trans, float* __restrict__ out) {
    __shared__ float w_s[256 * 6];
    for (int i = threadIdx.x; i < 1536; i += 256) w_s[i] = out_w[i];
    __syncthreads();
    int row = blockIdx.x * 256 + threadIdx.x;
    if (row >= BL) return;
    const float* hr = h + (size_t)row * 256;
    float corr[6];
    #pragma unroll
    for (int c = 0; c < 6; ++c) corr[c] = out_b[c];
    for (int k = 0; k < 256; ++k) {
        float hv = hr[k];
        #pragma unroll
        for (int c = 0; c < 6; ++c) corr[c] += hv * w_s[k * 6 + c];
    }
    float vx = corr[0], vy = corr[1], vz = corr[2];
    float n = sqrtf(vx * vx + vy * vy + vz * vz);
    float inv = 1.0f / (n + 1e-8f);
    float ax = vx * inv, ay = vy * inv, az = vz * inv;
    float s = sinf(n), cc = 1.0f - cosf(n);
    float K[9] = {0.f, -az, ay,  az, 0.f, -ax,  -ay, ax, 0.f};
    float K2[9];
    #pragma unroll
    for (int ii = 0; ii < 3; ++ii)
        #pragma unroll
        for (int jj = 0; jj < 3; ++jj)
            K2[ii * 3 + jj] = K[ii * 3 + 0] * K[0 * 3 + jj]
                            + K[ii * 3 + 1] * K[1 * 3 + jj]
                            + K[ii * 3 + 2] * K[2 * 3 + jj];
    float R[9];
    #pragma unroll
    for (int ii = 0; ii < 3; ++ii)
        #pragma unroll
        for (int jj = 0; jj < 3; ++jj)
            R[ii * 3 + jj] = (ii == jj ? 1.0f : 0.0f) + s * K[ii * 3 + jj] + cc * K2[ii * 3 + jj];
    const float* ro = rots + (size_t)row * 9;
    float* o = out + (size_t)row * 12;
    #pragma unroll
    for (int ii = 0; ii < 3; ++ii)
        #pragma unroll
        for (int jj = 0; jj < 3; ++jj)
            o[ii * 3 + jj] = ro[ii * 3 + 0] * R[0 * 3 + jj]
                           + ro[ii * 3 + 1] * R[1 * 3 + jj]
                           + ro[ii * 3 + 2] * R[2 * 3 + jj];
    float t0 = corr[3], t1 = corr[4], t2 = corr[5];
    const float* tr = trans + (size_t)row * 3;
    #pragma unroll
    for (int ii = 0; ii < 3; ++ii)
        o[9 + ii] = ro[ii * 3 + 0] * t0 + ro[ii * 3 + 1] * t1 + ro[ii * 3 + 2] * t2 + tr[ii];
}

extern "C" void kernel_launch(void* const* d_in, const int* in_sizes, int n_in,
                              void* d_out, int out_size, void* d_ws, size_t ws_size,
                              hipStream_t stream) {
    (void)in_sizes; (void)n_in; (void)out_size; (void)ws_size;
    const float* rots     = (const float*)d_in[0];
    const float* trans    = (const float*)d_in[1];
    const float* t        = (const float*)d_in[2];
    const float* single   = (const float*)d_in[3];
    const float* pair     = (const float*)d_in[4];
    const float* frame_w  = (const float*)d_in[5];
    const float* frame_b  = (const float*)d_in[6];
    const float* single_w = (const float*)d_in[7];
    const float* single_b = (const float*)d_in[8];
    const float* tw1      = (const float*)d_in[9];
    const float* tb1      = (const float*)d_in[10];
    const float* tw2      = (const float*)d_in[11];
    const float* tb2      = (const float*)d_in[12];
    const float* out_w    = (const float*)d_in[13];
    const float* out_b    = (const float*)d_in[14];
    const float* ag1      = (const float*)d_in[15];
    const float* abeta1   = (const float*)d_in[16];
    const float* apw1     = (const float*)d_in[17];
    const float* apb1     = (const float*)d_in[18];
    const float* wq       = (const float*)d_in[19];
    const float* wk       = (const float*)d_in[20];
    const float* wv       = (const float*)d_in[21];
    const float* pw       = (const float*)d_in[22];
    const float* wo       = (const float*)d_in[23];
    const float* wob      = (const float*)d_in[24];
    const float* ag2      = (const float*)d_in[25];
    const float* abeta2   = (const float*)d_in[26];
    const float* apw2     = (const float*)d_in[27];
    const float* apb2     = (const float*)d_in[28];
    const float* fw1      = (const float*)d_in[29];
    const float* fb1      = (const float*)d_in[30];
    const float* fw2      = (const float*)d_in[31];
    const float* fb2      = (const float*)d_in[32];

    float* ws = (float*)d_ws;
    float* time_cond = ws;                    // 512
    float* ss1 = time_cond + 512;             // 4096
    float* ss2 = ss1 + 4096;                  // 4096
    float* h   = ss2 + 4096;                  // 393216
    float* hh  = h + 393216;                  // 393216 (reused for h2)
    float* q   = hh + 393216;
    float* k_  = q + 393216;
    float* v   = k_ + 393216;
    float* attnout = v + 393216;
    float* mid = attnout + 393216;            // 1572864

    k_time<<<BB, 256, 0, stream>>>(t, tw1, tb1, tw2, tb2, time_cond);
    k_ss<<<dim3(NBLK, BB, 2), 512, 0, stream>>>(time_cond, apw1, apb1, apw2, apb2, ss1, ss2);
    k_init_h<<<BL, 256, 0, stream>>>(rots, trans, single, frame_w, frame_b,
                                     single_w, single_b, h);
    for (int n = 0; n < NBLK; ++n) {
        k_adaln<<<BL, 256, 0, stream>>>(h, ag1 + n * 256, abeta1 + n * 256,
                                        ss1 + (size_t)n * BB * 512, hh);
        k_gemm4<1, 1><<<BL / 4, 256, 0, stream>>>(hh, wq + (size_t)n * 65536,
                                                  nullptr, nullptr, q, 0);
        k_gemm4<1, 1><<<BL / 4, 256, 0, stream>>>(hh, wk + (size_t)n * 65536,
                                                  nullptr, nullptr, k_, 0);
        k_gemm4<1, 1><<<BL / 4, 256, 0, stream>>>(hh, wv + (size_t)n * 65536,
                                                  nullptr, nullptr, v, 0);
        k_attn<<<BL, 256, 0, stream>>>(q, k_, v, pair, pw + n * 512, attnout);
        k_gemm4<1, 1><<<BL / 4, 256, 0, stream>>>(attnout, wo + (size_t)n * 65536,
                                                  wob + n * 256, h, h, 1 | 4);
        k_adaln<<<BL, 256, 0, stream>>>(h, ag2 + n * 256, abeta2 + n * 256,
                                        ss2 + (size_t)n * BB * 512, hh);
        k_gemm4<4, 1><<<BL / 4, 256, 0, stream>>>(hh, fw1 + (size_t)n * 262144,
                                                  fb1 + n * 1024, nullptr, mid, 1 | 2);
        k_gemm4<1, 4><<<BL / 4, 256, 0, stream>>>(mid, fw2 + (size_t)n * 262144,
                                                  fb2 + n * 256, h, h, 1 | 4);
    }
    k_final<<<6, 256, 0, stream>>>(h, out_w, out_b, rots, trans, (float*)d_out);
}

// Round 2
// 3229.334 us; speedup vs baseline: 1.0433x; 1.0433x over previous
//
#include <hip/hip_runtime.h>
#include <math.h>

#define BB 2
#define LL 768
#define CC 256
#define CZ 64
#define NH 8
#define NBLK 4
#define HD 32
#define BL (BB*LL)   // 1536

__device__ __forceinline__ float gelu_exact(float x) {
    return 0.5f * x * (1.0f + erff(x * 0.70710678118654752f));
}

// ---------------- time embedding + MLP -> time_cond (B,256) ----------------
__global__ __launch_bounds__(256) void k_time(
        const float* __restrict__ t,
        const float* __restrict__ tw1, const float* __restrict__ tb1,
        const float* __restrict__ tw2, const float* __restrict__ tb2,
        float* __restrict__ time_cond) {
    __shared__ float temb[256];
    __shared__ float mid[1024];
    int b = blockIdx.x;
    int tid = threadIdx.x;
    if (tid < 128) {
        float f = expf(-logf(10000.0f) * (float)tid / 128.0f);
        float a = t[b] * f;
        temb[tid]       = cosf(a);
        temb[128 + tid] = sinf(a);
    }
    __syncthreads();
    #pragma unroll
    for (int m = 0; m < 4; ++m) {
        int col = tid + 256 * m;
        float acc = tb1[col];
        #pragma unroll 8
        for (int k = 0; k < 256; ++k) acc += temb[k] * tw1[(size_t)k * 1024 + col];
        mid[col] = gelu_exact(acc);
    }
    __syncthreads();
    float acc = tb2[tid];
    #pragma unroll 8
    for (int k = 0; k < 1024; ++k) acc += mid[k] * tw2[(size_t)k * 256 + tid];
    time_cond[b * 256 + tid] = acc;
}

// ---------------- adaln scale/shift tables ---------------------------------
__global__ __launch_bounds__(512) void k_ss(
        const float* __restrict__ tc,
        const float* __restrict__ apw1, const float* __restrict__ apb1,
        const float* __restrict__ apw2, const float* __restrict__ apb2,
        float* __restrict__ ss1, float* __restrict__ ss2) {
    int n = blockIdx.x, b = blockIdx.y, which = blockIdx.z;
    const float* apw = which ? apw2 : apw1;
    const float* apb = which ? apb2 : apb1;
    float* ss = which ? ss2 : ss1;
    __shared__ float tcl[256];
    int tid = threadIdx.x;
    if (tid < 256) tcl[tid] = tc[b * 256 + tid];
    __syncthreads();
    float acc = apb[n * 512 + tid];
    const float* w = apw + (size_t)n * 256 * 512 + tid;
    #pragma unroll 8
    for (int k = 0; k < 256; ++k) acc += tcl[k] * w[(size_t)k * 512];
    ss[(size_t)(n * BB + b) * 512 + tid] = acc;
}

// ---------------- h init ----------------------------------------------------
__global__ __launch_bounds__(256) void k_init_h(
        const float* __restrict__ rots, const float* __restrict__ trans,
        const float* __restrict__ single,
        const float* __restrict__ frame_w, const float* __restrict__ frame_b,
        const float* __restrict__ single_w, const float* __restrict__ single_b,
        float* __restrict__ h) {
    int row = blockIdx.x;
    int tid = threadIdx.x;
    __shared__ float ff[12];
    __shared__ float sr[256];
    if (tid < 9) ff[tid] = rots[(size_t)row * 9 + tid];
    else if (tid < 12) ff[tid] = trans[(size_t)row * 3 + (tid - 9)];
    sr[tid] = single[(size_t)row * 256 + tid];
    __syncthreads();
    float acc = frame_b[tid] + single_b[tid];
    #pragma unroll
    for (int k = 0; k < 12; ++k) acc += ff[k] * frame_w[k * 256 + tid];
    #pragma unroll 8
    for (int k = 0; k < 256; ++k) acc += sr[k] * single_w[k * 256 + tid];
    h[(size_t)row * 256 + tid] = acc;
}

// ---------------- adaln layernorm ------------------------------------------
__global__ __launch_bounds__(256) void k_adaln(
        const float* __restrict__ h, const float* __restrict__ g,
        const float* __restrict__ beta, const float* __restrict__ ss,
        float* __restrict__ out) {
    int row = blockIdx.x;
    int b = row / LL;
    int tid = threadIdx.x;
    float x = h[(size_t)row * 256 + tid];
    float s = x, sq = x * x;
    #pragma unroll
    for (int off = 32; off > 0; off >>= 1) {
        s  += __shfl_down(s,  off, 64);
        sq += __shfl_down(sq, off, 64);
    }
    __shared__ float red[8];
    int wave = tid >> 6, lane = tid & 63;
    if (lane == 0) { red[wave] = s; red[4 + wave] = sq; }
    __syncthreads();
    if (tid == 0) {
        float ts = red[0] + red[1] + red[2] + red[3];
        float tq = red[4] + red[5] + red[6] + red[7];
        float mu = ts * (1.0f / 256.0f);
        float var = tq * (1.0f / 256.0f) - mu * mu;
        red[0] = mu;
        red[1] = rsqrtf(var + 1e-5f);
    }
    __syncthreads();
    float mu = red[0], inv = red[1];
    float ln = (x - mu) * inv * g[tid] + beta[tid];
    float scale = ss[b * 512 + tid];
    float shift = ss[b * 512 + 256 + tid];
    out[(size_t)row * 256 + tid] = ln * (1.0f + scale) + shift;
}

// ---------------- generic tiled GEMM: 4 rows/block, 256 threads ------------
template<int NCOL, int KCH>
__global__ __launch_bounds__(256) void k_gemm4(
        const float* __restrict__ A, const float* __restrict__ W,
        const float* __restrict__ bias, const float* __restrict__ resid,
        float* __restrict__ out, int flags) {
    const int N = 256 * NCOL;
    const int K = 256 * KCH;
    int row0 = blockIdx.x * 4;
    int tid = threadIdx.x;
    __shared__ float a_s[4][256];
    float acc[4][NCOL];
    #pragma unroll
    for (int r = 0; r < 4; ++r)
        #pragma unroll
        for (int m = 0; m < NCOL; ++m) acc[r][m] = 0.f;

    for (int kc = 0; kc < KCH; ++kc) {
        if (kc) __syncthreads();
        {
            int r = tid >> 6, c4 = tid & 63;
            float4 av = reinterpret_cast<const float4*>(
                A + (size_t)(row0 + r) * K + kc * 256)[c4];
            *reinterpret_cast<float4*>(&a_s[r][c4 * 4]) = av;
        }
        __syncthreads();
        const float* Wp = W + (size_t)kc * 256 * N + tid;
        #pragma unroll 4
        for (int k = 0; k < 256; ++k) {
            float bv[NCOL];
            #pragma unroll
            for (int m = 0; m < NCOL; ++m) bv[m] = Wp[(size_t)k * N + 256 * m];
            #pragma unroll
            for (int r = 0; r < 4; ++r) {
                float a = a_s[r][k];
                #pragma unroll
                for (int m = 0; m < NCOL; ++m) acc[r][m] += a * bv[m];
            }
        }
    }
    #pragma unroll
    for (int r = 0; r < 4; ++r) {
        int row = row0 + r;
        #pragma unroll
        for (int m = 0; m < NCOL; ++m) {
            int col = tid + 256 * m;
            float v = acc[r][m];
            if (flags & 1) v += bias[col];
            if (flags & 2) v = gelu_exact(v);
            if (flags & 4) v += resid[(size_t)row * N + col];
            out[(size_t)row * N + col] = v;
        }
    }
}

// ---------------- fused QKV GEMM: 4 rows/block ------------------------------
__global__ __launch_bounds__(256) void k_gemm_qkv(
        const float* __restrict__ A,
        const float* __restrict__ Wq, const float* __restrict__ Wk,
        const float* __restrict__ Wv,
        float* __restrict__ q, float* __restrict__ k_,
        float* __restrict__ v) {
    int row0 = blockIdx.x * 4;
    int tid = threadIdx.x;
    __shared__ float a_s[4][256];
    {
        int r = tid >> 6, c4 = tid & 63;
        float4 av = reinterpret_cast<const float4*>(
            A + (size_t)(row0 + r) * 256)[c4];
        *reinterpret_cast<float4*>(&a_s[r][c4 * 4]) = av;
    }
    __syncthreads();
    float aq[4] = {0,0,0,0}, ak[4] = {0,0,0,0}, av_[4] = {0,0,0,0};
    #pragma unroll 4
    for (int k = 0; k < 256; ++k) {
        float wq_ = Wq[(size_t)k * 256 + tid];
        float wk_ = Wk[(size_t)k * 256 + tid];
        float wv_ = Wv[(size_t)k * 256 + tid];
        #pragma unroll
        for (int r = 0; r < 4; ++r) {
            float a = a_s[r][k];
            aq[r]  += a * wq_;
            ak[r]  += a * wk_;
            av_[r] += a * wv_;
        }
    }
    #pragma unroll
    for (int r = 0; r < 4; ++r) {
        size_t o = (size_t)(row0 + r) * 256 + tid;
        q[o] = aq[r]; k_[o] = ak[r]; v[o] = av_[r];
    }
}

// ---------------- pair bias precompute: pb[b][n*8+h][i][j] ------------------
// pb[(((b*32+nh)*768)+i)*768 + j] = sum_c pair[b,i,j,c] * pw[n][c][h]
__global__ __launch_bounds__(256) void k_pairbias(
        const float* __restrict__ pair, const float* __restrict__ pw,
        float* __restrict__ pb) {
    int row = blockIdx.x;            // b*768 + i
    int b = row / LL, i = row % LL;
    int tid = threadIdx.x;
    int j = blockIdx.y * 256 + tid;
    __shared__ float pw_t[2048];     // [nh][c] transposed
    #pragma unroll
    for (int x = 0; x < 8; ++x) {
        int idx = tid + 256 * x;
        int nh = idx >> 6, c = idx & 63;
        pw_t[idx] = pw[(nh >> 3) * 512 + c * 8 + (nh & 7)];
    }
    __syncthreads();
    float pr[64];
    {
        const float4* p4 = reinterpret_cast<const float4*>(
            pair + ((size_t)row * LL + j) * CZ);
        #pragma unroll
        for (int x = 0; x < 16; ++x) {
            float4 t4 = p4[x];
            pr[4*x] = t4.x; pr[4*x+1] = t4.y; pr[4*x+2] = t4.z; pr[4*x+3] = t4.w;
        }
    }
    #pragma unroll 4
    for (int nh = 0; nh < 32; ++nh) {
        const float4* wr = reinterpret_cast<const float4*>(&pw_t[nh * 64]);
        float s0 = 0.f, s1 = 0.f, s2 = 0.f, s3 = 0.f;
        #pragma unroll
        for (int c4 = 0; c4 < 16; ++c4) {
            float4 wv = wr[c4];
            s0 += pr[4*c4]   * wv.x;
            s1 += pr[4*c4+1] * wv.y;
            s2 += pr[4*c4+2] * wv.z;
            s3 += pr[4*c4+3] * wv.w;
        }
        pb[(((size_t)(b * 32 + nh)) * LL + i) * LL + j] = (s0 + s1) + (s2 + s3);
    }
}

// ---------------- flash attention with precomputed bias ---------------------
// grid 96 = b(2) x 48 i-tiles of 16. thread t: i=t&15, h=(t>>5), half=(t>>4)&1
__global__ __launch_bounds__(256, 2) void k_attn2(
        const float* __restrict__ q, const float* __restrict__ kk,
        const float* __restrict__ v, const float* __restrict__ pb,
        int n, float* __restrict__ outp) {
    int blk = blockIdx.x;
    int b = blk / 48;
    int i0 = (blk % 48) * 16;
    int t = threadIdx.x;
    int i_loc = t & 15;
    int half = (t >> 4) & 1;
    int h = t >> 5;
    int i = i0 + i_loc;

    __shared__ float K_s[32][256];
    __shared__ float V_s[32][256];

    float qr[32];
    {
        const float4* q4 = reinterpret_cast<const float4*>(
            q + ((size_t)(b * LL + i)) * 256 + h * 32);
        #pragma unroll
        for (int x = 0; x < 8; ++x) {
            float4 t4 = q4[x];
            qr[4*x] = t4.x; qr[4*x+1] = t4.y; qr[4*x+2] = t4.z; qr[4*x+3] = t4.w;
        }
    }
    const float* pbrow = pb + (((size_t)(b * 32 + n * 8 + h)) * LL + i) * LL;

    float O[16];
    #pragma unroll
    for (int x = 0; x < 16; ++x) O[x] = 0.f;
    float m = -1e30f, l = 0.f;
    const float scale = 0.17677669529663687f; // 1/sqrt(32)

    for (int jt = 0; jt < LL; jt += 32) {
        __syncthreads();   // protect previous tile's LDS reads
        {
            const float4* ksrc = reinterpret_cast<const float4*>(
                kk + ((size_t)(b * LL) + jt) * 256);
            const float4* vsrc = reinterpret_cast<const float4*>(
                v + ((size_t)(b * LL) + jt) * 256);
            #pragma unroll
            for (int x = 0; x < 8; ++x) {
                int idx = t + 256 * x;
                reinterpret_cast<float4*>(K_s)[idx] = ksrc[idx];
                reinterpret_cast<float4*>(V_s)[idx] = vsrc[idx];
            }
        }
        float bias[32];
        {
            const float4* b4 = reinterpret_cast<const float4*>(pbrow + jt);
            #pragma unroll
            for (int x = 0; x < 8; ++x) {
                float4 t4 = b4[x];
                bias[4*x] = t4.x; bias[4*x+1] = t4.y;
                bias[4*x+2] = t4.z; bias[4*x+3] = t4.w;
            }
        }
        __syncthreads();   // staging visible (also drains bias loads)
        #pragma unroll
        for (int j = 0; j < 32; ++j) {
            const float4* kr = reinterpret_cast<const float4*>(&K_s[j][h * 32]);
            float a0 = 0.f, a1 = 0.f, a2 = 0.f, a3 = 0.f;
            #pragma unroll
            for (int x = 0; x < 8; ++x) {
                float4 kv = kr[x];
                a0 += qr[4*x]   * kv.x;
                a1 += qr[4*x+1] * kv.y;
                a2 += qr[4*x+2] * kv.z;
                a3 += qr[4*x+3] * kv.w;
            }
            float s = ((a0 + a1) + (a2 + a3)) * scale + bias[j];
            float mn = fmaxf(m, s);
            float alpha = __expf(m - mn);
            float e = __expf(s - mn);
            l = l * alpha + e;
            m = mn;
            const float4* vr = reinterpret_cast<const float4*>(
                &V_s[j][h * 32 + half * 16]);
            #pragma unroll
            for (int x = 0; x < 4; ++x) {
                float4 vv = vr[x];
                O[4*x]   = O[4*x]   * alpha + e * vv.x;
                O[4*x+1] = O[4*x+1] * alpha + e * vv.y;
                O[4*x+2] = O[4*x+2] * alpha + e * vv.z;
                O[4*x+3] = O[4*x+3] * alpha + e * vv.w;
            }
        }
    }
    float inv = 1.0f / l;
    float* op = outp + ((size_t)(b * LL + i)) * 256 + h * 32 + half * 16;
    #pragma unroll
    for (int x = 0; x < 4; ++x) {
        float4 o4 = make_float4(O[4*x] * inv, O[4*x+1] * inv,
                                O[4*x+2] * inv, O[4*x+3] * inv);
        reinterpret_cast<float4*>(op)[x] = o4;
    }
}

// ---------------- fallback fused attention (reads pair directly) ------------
__global__ __launch_bounds__(256) void k_attn(
        const float* __restrict__ q, const float* __restrict__ kk,
        const float* __restrict__ v, const float* __restrict__ pair,
        const float* __restrict__ pw, float* __restrict__ outp) {
    int blk = blockIdx.x;
    int b = blk / LL, i = blk % LL;
    int tid = threadIdx.x;
    __shared__ float q_s[256];
    __shared__ float pw_s[CZ * NH];
    __shared__ float lg[NH][LL];
    __shared__ float part[8][256];
    __shared__ float invs[NH];
    size_t rowq = (size_t)(b * LL + i) * 256;
    q_s[tid] = q[rowq + tid];
    pw_s[tid] = pw[tid];
    pw_s[tid + 256] = pw[tid + 256];
    __syncthreads();

    const float scale = 0.17677669529663687f;
    for (int j = tid; j < LL; j += 256) {
        const float4* k4 = reinterpret_cast<const float4*>(kk + (size_t)(b * LL + j) * 256);
        const float4* q4 = reinterpret_cast<const float4*>(q_s);
        float dot[NH];
        #pragma unroll
        for (int h = 0; h < NH; ++h) {
            float sx = 0.f, sy = 0.f, sz = 0.f, sw = 0.f;
            #pragma unroll
            for (int dd = 0; dd < 8; ++dd) {
                float4 kv = k4[h * 8 + dd];
                float4 qv = q4[h * 8 + dd];
                sx += qv.x * kv.x; sy += qv.y * kv.y;
                sz += qv.z * kv.z; sw += qv.w * kv.w;
            }
            dot[h] = (sx + sy) + (sz + sw);
        }
        const float4* p4 = reinterpret_cast<const float4*>(
            pair + ((size_t)(b * LL + i) * LL + j) * CZ);
        float bias[NH];
        #pragma unroll
        for (int h = 0; h < NH; ++h) bias[h] = 0.f;
        #pragma unroll
        for (int c4 = 0; c4 < 16; ++c4) {
            float4 pv = p4[c4];
            int c = c4 * 4;
            #pragma unroll
            for (int h = 0; h < NH; ++h)
                bias[h] += pv.x * pw_s[(c + 0) * NH + h] + pv.y * pw_s[(c + 1) * NH + h]
                         + pv.z * pw_s[(c + 2) * NH + h] + pv.w * pw_s[(c + 3) * NH + h];
        }
        #pragma unroll
        for (int h = 0; h < NH; ++h) lg[h][j] = dot[h] * scale + bias[h];
    }
    __syncthreads();

    int wave = tid >> 6, lane = tid & 63;
    for (int h = wave; h < NH; h += 4) {
        float mx = -1e30f;
        for (int j = lane; j < LL; j += 64) mx = fmaxf(mx, lg[h][j]);
        #pragma unroll
        for (int off = 32; off > 0; off >>= 1) mx = fmaxf(mx, __shfl_xor(mx, off, 64));
        float sm = 0.f;
        for (int j = lane; j < LL; j += 64) {
            float e = __expf(lg[h][j] - mx);
            lg[h][j] = e;
            sm += e;
        }
        #pragma unroll
        for (int off = 32; off > 0; off >>= 1) sm += __shfl_xor(sm, off, 64);
        if (lane == 0) invs[h] = 1.0f / sm;
    }
    __syncthreads();

    int g = tid >> 5, d = tid & 31;
    float acc[NH];
    #pragma unroll
    for (int h = 0; h < NH; ++h) acc[h] = 0.f;
    for (int j = g; j < LL; j += 8) {
        const float* vr = v + (size_t)(b * LL + j) * 256;
        #pragma unroll
        for (int h = 0; h < NH; ++h) acc[h] += lg[h][j] * vr[h * 32 + d];
    }
    #pragma unroll
    for (int h = 0; h < NH; ++h) part[g][h * 32 + d] = acc[h];
    __syncthreads();
    float sum = 0.f;
    #pragma unroll
    for (int g2 = 0; g2 < 8; ++g2) sum += part[g2][tid];
    outp[rowq + tid] = sum * invs[tid >> 5];
}

// ---------------- final frame update ---------------------------------------
__global__ __launch_bounds__(256) void k_final(
        const float* __restrict__ h, const float* __restrict__ out_w,
        const float* __restrict__ out_b, const float* __restrict__ rots,
        const float* __restrict__ trans, float* __restrict__ out) {
    __shared__ float w_s[256 * 6];
    for (int i = threadIdx.x; i < 1536; i += 256) w_s[i] = out_w[i];
    __syncthreads();
    int row = blockIdx.x * 256 + threadIdx.x;
    if (row >= BL) return;
    const float* hr = h + (size_t)row * 256;
    float corr[6];
    #pragma unroll
    for (int c = 0; c < 6; ++c) corr[c] = out_b[c];
    for (int k = 0; k < 256; ++k) {
        float hv = hr[k];
        #pragma unroll
        for (int c = 0; c < 6; ++c) corr[c] += hv * w_s[k * 6 + c];
    }
    float vx = corr[0], vy = corr[1], vz = corr[2];
    float n = sqrtf(vx * vx + vy * vy + vz * vz);
    float inv = 1.0f / (n + 1e-8f);
    float ax = vx * inv, ay = vy * inv, az = vz * inv;
    float s = sinf(n), cc = 1.0f - cosf(n);
    float K[9] = {0.f, -az, ay,  az, 0.f, -ax,  -ay, ax, 0.f};
    float K2[9];
    #pragma unroll
    for (int ii = 0; ii < 3; ++ii)
        #pragma unroll
        for (int jj = 0; jj < 3; ++jj)
            K2[ii * 3 + jj] = K[ii * 3 + 0] * K[0 * 3 + jj]
                            + K[ii * 3 + 1] * K[1 * 3 + jj]
                            + K[ii * 3 + 2] * K[2 * 3 + jj];
    float R[9];
    #pragma unroll
    for (int ii = 0; ii < 3; ++ii)
        #pragma unroll
        for (int jj = 0; jj < 3; ++jj)
            R[ii * 3 + jj] = (ii == jj ? 1.0f : 0.0f) + s * K[ii * 3 + jj] + cc * K2[ii * 3 + jj];
    const float* ro = rots + (size_t)row * 9;
    float* o = out + (size_t)row * 12;
    #pragma unroll
    for (int ii = 0; ii < 3; ++ii)
        #pragma unroll
        for (int jj = 0; jj < 3; ++jj)
            o[ii * 3 + jj] = ro[ii * 3 + 0] * R[0 * 3 + jj]
                           + ro[ii * 3 + 1] * R[1 * 3 + jj]
                           + ro[ii * 3 + 2] * R[2 * 3 + jj];
    float t0 = corr[3], t1 = corr[4], t2 = corr[5];
    const float* tr = trans + (size_t)row * 3;
    #pragma unroll
    for (int ii = 0; ii < 3; ++ii)
        o[9 + ii] = ro[ii * 3 + 0] * t0 + ro[ii * 3 + 1] * t1 + ro[ii * 3 + 2] * t2 + tr[ii];
}

extern "C" void kernel_launch(void* const* d_in, const int* in_sizes, int n_in,
                              void* d_out, int out_size, void* d_ws, size_t ws_size,
                              hipStream_t stream) {
    (void)in_sizes; (void)n_in; (void)out_size;
    const float* rots     = (const float*)d_in[0];
    const float* trans    = (const float*)d_in[1];
    const float* t        = (const float*)d_in[2];
    const float* single   = (const float*)d_in[3];
    const float* pair     = (const float*)d_in[4];
    const float* frame_w  = (const float*)d_in[5];
    const float* frame_b  = (const float*)d_in[6];
    const float* single_w = (const float*)d_in[7];
    const float* single_b = (const float*)d_in[8];
    const float* tw1      = (const float*)d_in[9];
    const float* tb1      = (const float*)d_in[10];
    const float* tw2      = (const float*)d_in[11];
    const float* tb2      = (const float*)d_in[12];
    const float* out_w    = (const float*)d_in[13];
    const float* out_b    = (const float*)d_in[14];
    const float* ag1      = (const float*)d_in[15];
    const float* abeta1   = (const float*)d_in[16];
    const float* apw1     = (const float*)d_in[17];
    const float* apb1     = (const float*)d_in[18];
    const float* wq       = (const float*)d_in[19];
    const float* wk       = (const float*)d_in[20];
    const float* wv       = (const float*)d_in[21];
    const float* pw       = (const float*)d_in[22];
    const float* wo       = (const float*)d_in[23];
    const float* wob      = (const float*)d_in[24];
    const float* ag2      = (const float*)d_in[25];
    const float* abeta2   = (const float*)d_in[26];
    const float* apw2     = (const float*)d_in[27];
    const float* apb2     = (const float*)d_in[28];
    const float* fw1      = (const float*)d_in[29];
    const float* fb1      = (const float*)d_in[30];
    const float* fw2      = (const float*)d_in[31];
    const float* fb2      = (const float*)d_in[32];

    float* ws = (float*)d_ws;
    float* time_cond = ws;                    // 512
    float* ss1 = time_cond + 512;             // 4096
    float* ss2 = ss1 + 4096;                  // 4096
    float* h   = ss2 + 4096;                  // 393216
    float* hh  = h + 393216;
    float* q   = hh + 393216;
    float* k_  = q + 393216;
    float* v   = k_ + 393216;
    float* attnout = v + 393216;
    float* mid = attnout + 393216;            // 1572864
    float* pb  = mid + 1572864;               // 37748736 floats (151 MB)

    const size_t base_floats = 3940864ull;
    const size_t need = (base_floats + 37748736ull) * 4ull;
    const bool big = ws_size >= need;

    k_time<<<BB, 256, 0, stream>>>(t, tw1, tb1, tw2, tb2, time_cond);
    k_ss<<<dim3(NBLK, BB, 2), 512, 0, stream>>>(time_cond, apw1, apb1, apw2, apb2, ss1, ss2);
    k_init_h<<<BL, 256, 0, stream>>>(rots, trans, single, frame_w, frame_b,
                                     single_w, single_b, h);
    if (big)
        k_pairbias<<<dim3(BL, 3), 256, 0, stream>>>(pair, pw, pb);

    for (int n = 0; n < NBLK; ++n) {
        k_adaln<<<BL, 256, 0, stream>>>(h, ag1 + n * 256, abeta1 + n * 256,
                                        ss1 + (size_t)n * BB * 512, hh);
        k_gemm_qkv<<<BL / 4, 256, 0, stream>>>(hh, wq + (size_t)n * 65536,
                                               wk + (size_t)n * 65536,
                                               wv + (size_t)n * 65536, q, k_, v);
        if (big)
            k_attn2<<<96, 256, 0, stream>>>(q, k_, v, pb, n, attnout);
        else
            k_attn<<<BL, 256, 0, stream>>>(q, k_, v, pair, pw + n * 512, attnout);
        k_gemm4<1, 1><<<BL / 4, 256, 0, stream>>>(attnout, wo + (size_t)n * 65536,
                                                  wob + n * 256, h, h, 1 | 4);
        k_adaln<<<BL, 256, 0, stream>>>(h, ag2 + n * 256, abeta2 + n * 256,
                                        ss2 + (size_t)n * BB * 512, hh);
        k_gemm4<4, 1><<<BL / 4, 256, 0, stream>>>(hh, fw1 + (size_t)n * 262144,
                                                  fb1 + n * 1024, nullptr, mid, 1 | 2);
        k_gemm4<1, 4><<<BL / 4, 256, 0, stream>>>(mid, fw2 + (size_t)n * 262144,
                                                  fb2 + n * 256, h, h, 1 | 4);
    }
    k_final<<<6, 256, 0, stream>>>(h, out_w, out_b, rots, trans, (float*)d_out);
}

// Round 3
// 1954.399 us; speedup vs baseline: 1.7238x; 1.6523x over previous
//
#include <hip/hip_runtime.h>
#include <math.h>

#define BB 2
#define LL 768
#define CC 256
#define CZ 64
#define NH 8
#define NBLK 4
#define HD 32
#define BL (BB*LL)   // 1536

__device__ __forceinline__ float gelu_exact(float x) {
    return 0.5f * x * (1.0f + erff(x * 0.70710678118654752f));
}

// ---------------- time embedding + MLP -> time_cond (B,256) ----------------
__global__ __launch_bounds__(256) void k_time(
        const float* __restrict__ t,
        const float* __restrict__ tw1, const float* __restrict__ tb1,
        const float* __restrict__ tw2, const float* __restrict__ tb2,
        float* __restrict__ time_cond) {
    __shared__ float temb[256];
    __shared__ float mid[1024];
    int b = blockIdx.x;
    int tid = threadIdx.x;
    if (tid < 128) {
        float f = expf(-logf(10000.0f) * (float)tid / 128.0f);
        float a = t[b] * f;
        temb[tid]       = cosf(a);
        temb[128 + tid] = sinf(a);
    }
    __syncthreads();
    #pragma unroll
    for (int m = 0; m < 4; ++m) {
        int col = tid + 256 * m;
        float acc = tb1[col];
        #pragma unroll 8
        for (int k = 0; k < 256; ++k) acc += temb[k] * tw1[(size_t)k * 1024 + col];
        mid[col] = gelu_exact(acc);
    }
    __syncthreads();
    float acc = tb2[tid];
    #pragma unroll 8
    for (int k = 0; k < 1024; ++k) acc += mid[k] * tw2[(size_t)k * 256 + tid];
    time_cond[b * 256 + tid] = acc;
}

// ---------------- adaln scale/shift tables ---------------------------------
__global__ __launch_bounds__(512) void k_ss(
        const float* __restrict__ tc,
        const float* __restrict__ apw1, const float* __restrict__ apb1,
        const float* __restrict__ apw2, const float* __restrict__ apb2,
        float* __restrict__ ss1, float* __restrict__ ss2) {
    int n = blockIdx.x, b = blockIdx.y, which = blockIdx.z;
    const float* apw = which ? apw2 : apw1;
    const float* apb = which ? apb2 : apb1;
    float* ss = which ? ss2 : ss1;
    __shared__ float tcl[256];
    int tid = threadIdx.x;
    if (tid < 256) tcl[tid] = tc[b * 256 + tid];
    __syncthreads();
    float acc = apb[n * 512 + tid];
    const float* w = apw + (size_t)n * 256 * 512 + tid;
    #pragma unroll 8
    for (int k = 0; k < 256; ++k) acc += tcl[k] * w[(size_t)k * 512];
    ss[(size_t)(n * BB + b) * 512 + tid] = acc;
}

// ---------------- h init ----------------------------------------------------
__global__ __launch_bounds__(256) void k_init_h(
        const float* __restrict__ rots, const float* __restrict__ trans,
        const float* __restrict__ single,
        const float* __restrict__ frame_w, const float* __restrict__ frame_b,
        const float* __restrict__ single_w, const float* __restrict__ single_b,
        float* __restrict__ h) {
    int row = blockIdx.x;
    int tid = threadIdx.x;
    __shared__ float ff[12];
    __shared__ float sr[256];
    if (tid < 9) ff[tid] = rots[(size_t)row * 9 + tid];
    else if (tid < 12) ff[tid] = trans[(size_t)row * 3 + (tid - 9)];
    sr[tid] = single[(size_t)row * 256 + tid];
    __syncthreads();
    float acc = frame_b[tid] + single_b[tid];
    #pragma unroll
    for (int k = 0; k < 12; ++k) acc += ff[k] * frame_w[k * 256 + tid];
    #pragma unroll 8
    for (int k = 0; k < 256; ++k) acc += sr[k] * single_w[k * 256 + tid];
    h[(size_t)row * 256 + tid] = acc;
}

// ---------------- adaln layernorm ------------------------------------------
__global__ __launch_bounds__(256) void k_adaln(
        const float* __restrict__ h, const float* __restrict__ g,
        const float* __restrict__ beta, const float* __restrict__ ss,
        float* __restrict__ out) {
    int row = blockIdx.x;
    int b = row / LL;
    int tid = threadIdx.x;
    float x = h[(size_t)row * 256 + tid];
    float s = x, sq = x * x;
    #pragma unroll
    for (int off = 32; off > 0; off >>= 1) {
        s  += __shfl_down(s,  off, 64);
        sq += __shfl_down(sq, off, 64);
    }
    __shared__ float red[8];
    int wave = tid >> 6, lane = tid & 63;
    if (lane == 0) { red[wave] = s; red[4 + wave] = sq; }
    __syncthreads();
    if (tid == 0) {
        float ts = red[0] + red[1] + red[2] + red[3];
        float tq = red[4] + red[5] + red[6] + red[7];
        float mu = ts * (1.0f / 256.0f);
        float var = tq * (1.0f / 256.0f) - mu * mu;
        red[0] = mu;
        red[1] = rsqrtf(var + 1e-5f);
    }
    __syncthreads();
    float mu = red[0], inv = red[1];
    float ln = (x - mu) * inv * g[tid] + beta[tid];
    float scale = ss[b * 512 + tid];
    float shift = ss[b * 512 + 256 + tid];
    out[(size_t)row * 256 + tid] = ln * (1.0f + scale) + shift;
}

// ---------------- generic tiled GEMM: 4 rows/block, 256 threads ------------
template<int NCOL, int KCH>
__global__ __launch_bounds__(256) void k_gemm4(
        const float* __restrict__ A, const float* __restrict__ W,
        const float* __restrict__ bias, const float* __restrict__ resid,
        float* __restrict__ out, int flags) {
    const int N = 256 * NCOL;
    const int K = 256 * KCH;
    int row0 = blockIdx.x * 4;
    int tid = threadIdx.x;
    __shared__ float a_s[4][256];
    float acc[4][NCOL];
    #pragma unroll
    for (int r = 0; r < 4; ++r)
        #pragma unroll
        for (int m = 0; m < NCOL; ++m) acc[r][m] = 0.f;

    for (int kc = 0; kc < KCH; ++kc) {
        if (kc) __syncthreads();
        {
            int r = tid >> 6, c4 = tid & 63;
            float4 av = reinterpret_cast<const float4*>(
                A + (size_t)(row0 + r) * K + kc * 256)[c4];
            *reinterpret_cast<float4*>(&a_s[r][c4 * 4]) = av;
        }
        __syncthreads();
        const float* Wp = W + (size_t)kc * 256 * N + tid;
        #pragma unroll 4
        for (int k = 0; k < 256; ++k) {
            float bv[NCOL];
            #pragma unroll
            for (int m = 0; m < NCOL; ++m) bv[m] = Wp[(size_t)k * N + 256 * m];
            #pragma unroll
            for (int r = 0; r < 4; ++r) {
                float a = a_s[r][k];
                #pragma unroll
                for (int m = 0; m < NCOL; ++m) acc[r][m] += a * bv[m];
            }
        }
    }
    #pragma unroll
    for (int r = 0; r < 4; ++r) {
        int row = row0 + r;
        #pragma unroll
        for (int m = 0; m < NCOL; ++m) {
            int col = tid + 256 * m;
            float v = acc[r][m];
            if (flags & 1) v += bias[col];
            if (flags & 2) v = gelu_exact(v);
            if (flags & 4) v += resid[(size_t)row * N + col];
            out[(size_t)row * N + col] = v;
        }
    }
}

// ---------------- fused QKV GEMM: 4 rows/block ------------------------------
__global__ __launch_bounds__(256) void k_gemm_qkv(
        const float* __restrict__ A,
        const float* __restrict__ Wq, const float* __restrict__ Wk,
        const float* __restrict__ Wv,
        float* __restrict__ q, float* __restrict__ k_,
        float* __restrict__ v) {
    int row0 = blockIdx.x * 4;
    int tid = threadIdx.x;
    __shared__ float a_s[4][256];
    {
        int r = tid >> 6, c4 = tid & 63;
        float4 av = reinterpret_cast<const float4*>(
            A + (size_t)(row0 + r) * 256)[c4];
        *reinterpret_cast<float4*>(&a_s[r][c4 * 4]) = av;
    }
    __syncthreads();
    float aq[4] = {0,0,0,0}, ak[4] = {0,0,0,0}, av_[4] = {0,0,0,0};
    #pragma unroll 4
    for (int k = 0; k < 256; ++k) {
        float wq_ = Wq[(size_t)k * 256 + tid];
        float wk_ = Wk[(size_t)k * 256 + tid];
        float wv_ = Wv[(size_t)k * 256 + tid];
        #pragma unroll
        for (int r = 0; r < 4; ++r) {
            float a = a_s[r][k];
            aq[r]  += a * wq_;
            ak[r]  += a * wk_;
            av_[r] += a * wv_;
        }
    }
    #pragma unroll
    for (int r = 0; r < 4; ++r) {
        size_t o = (size_t)(row0 + r) * 256 + tid;
        q[o] = aq[r]; k_[o] = ak[r]; v[o] = av_[r];
    }
}

// ---------------- pair bias precompute: pb[b][n*8+h][i][j] ------------------
__global__ __launch_bounds__(256) void k_pairbias(
        const float* __restrict__ pair, const float* __restrict__ pw,
        float* __restrict__ pb) {
    int row = blockIdx.x;            // b*768 + i
    int b = row / LL, i = row % LL;
    int tid = threadIdx.x;
    int j = blockIdx.y * 256 + tid;
    __shared__ float pw_t[2048];     // [nh][c] transposed
    #pragma unroll
    for (int x = 0; x < 8; ++x) {
        int idx = tid + 256 * x;
        int nh = idx >> 6, c = idx & 63;
        pw_t[idx] = pw[(nh >> 3) * 512 + c * 8 + (nh & 7)];
    }
    __syncthreads();
    float pr[64];
    {
        const float4* p4 = reinterpret_cast<const float4*>(
            pair + ((size_t)row * LL + j) * CZ);
        #pragma unroll
        for (int x = 0; x < 16; ++x) {
            float4 t4 = p4[x];
            pr[4*x] = t4.x; pr[4*x+1] = t4.y; pr[4*x+2] = t4.z; pr[4*x+3] = t4.w;
        }
    }
    #pragma unroll 4
    for (int nh = 0; nh < 32; ++nh) {
        const float4* wr = reinterpret_cast<const float4*>(&pw_t[nh * 64]);
        float s0 = 0.f, s1 = 0.f, s2 = 0.f, s3 = 0.f;
        #pragma unroll
        for (int c4 = 0; c4 < 16; ++c4) {
            float4 wv = wr[c4];
            s0 += pr[4*c4]   * wv.x;
            s1 += pr[4*c4+1] * wv.y;
            s2 += pr[4*c4+2] * wv.z;
            s3 += pr[4*c4+3] * wv.w;
        }
        pb[(((size_t)(b * 32 + nh)) * LL + i) * LL + j] = (s0 + s1) + (s2 + s3);
    }
}

// ---------------- attention v3: register logits, two-pass softmax ----------
// grid: b(2) x h(8) x it(48) = 768 blocks, 256 threads.
// thread t: i = t&15 (query row in tile), jg = t>>4 (j chunk of 48).
__global__ __launch_bounds__(256) void k_attn3(
        const float* __restrict__ q, const float* __restrict__ kk,
        const float* __restrict__ v, const float* __restrict__ pb,
        int n, float* __restrict__ outp) {
    int blk = blockIdx.x;
    int it = blk % 48;
    int bh = blk / 48;
    int h = bh % NH;
    int b = bh / NH;
    int i0 = it * 16;
    int t = threadIdx.x;
    int i = t & 15;
    int jg = t >> 4;
    int wave = t >> 6, lane = t & 63;

    __shared__ float q_s[16][32];
    __shared__ float red_m[4][16];
    __shared__ float red_l[4][16];
    __shared__ float linv[16];
    __shared__ float part[4][16][32];

    if (t < 128) {
        int qi = t >> 3, x = t & 7;
        reinterpret_cast<float4*>(&q_s[qi][x * 4])[0] =
            reinterpret_cast<const float4*>(
                q + ((size_t)(b * LL + i0 + qi)) * 256 + h * 32)[x];
    }
    __syncthreads();

    float qr[32];
    #pragma unroll
    for (int x = 0; x < 8; ++x) {
        float4 t4 = reinterpret_cast<const float4*>(&q_s[i][0])[x];
        qr[4*x] = t4.x; qr[4*x+1] = t4.y; qr[4*x+2] = t4.z; qr[4*x+3] = t4.w;
    }

    const float* pbrow = pb + (((size_t)(b * 32 + n * NH + h)) * LL + (i0 + i)) * LL + jg * 48;
    const float* Kbase = kk + ((size_t)(b * LL + jg * 48)) * 256 + h * 32;
    const float* Vbase = v  + ((size_t)(b * LL + jg * 48)) * 256 + h * 32;
    const float scale = 0.17677669529663687f; // 1/sqrt(32)

    // phase 1: 48 logits per thread, in registers
    float lg[48];
    #pragma unroll
    for (int jj = 0; jj < 48; ++jj) {
        const float4* kr = reinterpret_cast<const float4*>(Kbase + (size_t)jj * 256);
        float a0 = 0.f, a1 = 0.f, a2 = 0.f, a3 = 0.f;
        #pragma unroll
        for (int x = 0; x < 8; ++x) {
            float4 kv = kr[x];
            a0 += qr[4*x]   * kv.x;
            a1 += qr[4*x+1] * kv.y;
            a2 += qr[4*x+2] * kv.z;
            a3 += qr[4*x+3] * kv.w;
        }
        lg[jj] = ((a0 + a1) + (a2 + a3)) * scale;
    }
    #pragma unroll
    for (int x = 0; x < 12; ++x) {
        float4 bv = reinterpret_cast<const float4*>(pbrow)[x];
        lg[4*x]   += bv.x; lg[4*x+1] += bv.y;
        lg[4*x+2] += bv.z; lg[4*x+3] += bv.w;
    }

    // row max across 16 jg-threads: 4 in-wave (lanes ^16, ^32) + 4 waves via LDS
    float m = -1e30f;
    #pragma unroll
    for (int jj = 0; jj < 48; ++jj) m = fmaxf(m, lg[jj]);
    m = fmaxf(m, __shfl_xor(m, 16, 64));
    m = fmaxf(m, __shfl_xor(m, 32, 64));
    if (lane < 16) red_m[wave][lane] = m;
    __syncthreads();
    m = fmaxf(fmaxf(red_m[0][i], red_m[1][i]), fmaxf(red_m[2][i], red_m[3][i]));

    // exp + row sum
    float l = 0.f;
    #pragma unroll
    for (int jj = 0; jj < 48; ++jj) {
        float e = __expf(lg[jj] - m);
        lg[jj] = e;
        l += e;
    }
    l += __shfl_xor(l, 16, 64);
    l += __shfl_xor(l, 32, 64);
    if (lane < 16) red_l[wave][lane] = l;
    __syncthreads();
    l = (red_l[0][i] + red_l[1][i]) + (red_l[2][i] + red_l[3][i]);
    if (t < 16) linv[t] = 1.0f / ((red_l[0][t] + red_l[1][t]) + (red_l[2][t] + red_l[3][t]));

    // phase 2: O = P V (partial over this thread's 48 j)
    float O[32];
    #pragma unroll
    for (int x = 0; x < 32; ++x) O[x] = 0.f;
    #pragma unroll
    for (int jj = 0; jj < 48; ++jj) {
        float e = lg[jj];
        const float4* vr = reinterpret_cast<const float4*>(Vbase + (size_t)jj * 256);
        #pragma unroll
        for (int x = 0; x < 8; ++x) {
            float4 vv = vr[x];
            O[4*x]   += e * vv.x;
            O[4*x+1] += e * vv.y;
            O[4*x+2] += e * vv.z;
            O[4*x+3] += e * vv.w;
        }
    }
    #pragma unroll
    for (int x = 0; x < 32; ++x) {
        O[x] += __shfl_xor(O[x], 16, 64);
        O[x] += __shfl_xor(O[x], 32, 64);
    }
    if (lane < 16) {
        #pragma unroll
        for (int x = 0; x < 8; ++x) {
            float4 o4 = make_float4(O[4*x], O[4*x+1], O[4*x+2], O[4*x+3]);
            reinterpret_cast<float4*>(&part[wave][lane][4*x])[0] = o4;
        }
    }
    __syncthreads();
    #pragma unroll
    for (int o = 0; o < 2; ++o) {
        int idx = t + o * 256;
        int oi = idx >> 5, od = idx & 31;
        float s = (part[0][oi][od] + part[1][oi][od])
                + (part[2][oi][od] + part[3][oi][od]);
        outp[((size_t)(b * LL + i0 + oi)) * 256 + h * 32 + od] = s * linv[oi];
    }
}

// ---------------- fallback fused attention (reads pair directly) ------------
__global__ __launch_bounds__(256) void k_attn(
        const float* __restrict__ q, const float* __restrict__ kk,
        const float* __restrict__ v, const float* __restrict__ pair,
        const float* __restrict__ pw, float* __restrict__ outp) {
    int blk = blockIdx.x;
    int b = blk / LL, i = blk % LL;
    int tid = threadIdx.x;
    __shared__ float q_s[256];
    __shared__ float pw_s[CZ * NH];
    __shared__ float lg[NH][LL];
    __shared__ float part[8][256];
    __shared__ float invs[NH];
    size_t rowq = (size_t)(b * LL + i) * 256;
    q_s[tid] = q[rowq + tid];
    pw_s[tid] = pw[tid];
    pw_s[tid + 256] = pw[tid + 256];
    __syncthreads();

    const float scale = 0.17677669529663687f;
    for (int j = tid; j < LL; j += 256) {
        const float4* k4 = reinterpret_cast<const float4*>(kk + (size_t)(b * LL + j) * 256);
        const float4* q4 = reinterpret_cast<const float4*>(q_s);
        float dot[NH];
        #pragma unroll
        for (int h = 0; h < NH; ++h) {
            float sx = 0.f, sy = 0.f, sz = 0.f, sw = 0.f;
            #pragma unroll
            for (int dd = 0; dd < 8; ++dd) {
                float4 kv = k4[h * 8 + dd];
                float4 qv = q4[h * 8 + dd];
                sx += qv.x * kv.x; sy += qv.y * kv.y;
                sz += qv.z * kv.z; sw += qv.w * kv.w;
            }
            dot[h] = (sx + sy) + (sz + sw);
        }
        const float4* p4 = reinterpret_cast<const float4*>(
            pair + ((size_t)(b * LL + i) * LL + j) * CZ);
        float bias[NH];
        #pragma unroll
        for (int h = 0; h < NH; ++h) bias[h] = 0.f;
        #pragma unroll
        for (int c4 = 0; c4 < 16; ++c4) {
            float4 pv = p4[c4];
            int c = c4 * 4;
            #pragma unroll
            for (int h = 0; h < NH; ++h)
                bias[h] += pv.x * pw_s[(c + 0) * NH + h] + pv.y * pw_s[(c + 1) * NH + h]
                         + pv.z * pw_s[(c + 2) * NH + h] + pv.w * pw_s[(c + 3) * NH + h];
        }
        #pragma unroll
        for (int h = 0; h < NH; ++h) lg[h][j] = dot[h] * scale + bias[h];
    }
    __syncthreads();

    int wave = tid >> 6, lane = tid & 63;
    for (int h = wave; h < NH; h += 4) {
        float mx = -1e30f;
        for (int j = lane; j < LL; j += 64) mx = fmaxf(mx, lg[h][j]);
        #pragma unroll
        for (int off = 32; off > 0; off >>= 1) mx = fmaxf(mx, __shfl_xor(mx, off, 64));
        float sm = 0.f;
        for (int j = lane; j < LL; j += 64) {
            float e = __expf(lg[h][j] - mx);
            lg[h][j] = e;
            sm += e;
        }
        #pragma unroll
        for (int off = 32; off > 0; off >>= 1) sm += __shfl_xor(sm, off, 64);
        if (lane == 0) invs[h] = 1.0f / sm;
    }
    __syncthreads();

    int g = tid >> 5, d = tid & 31;
    float acc[NH];
    #pragma unroll
    for (int h = 0; h < NH; ++h) acc[h] = 0.f;
    for (int j = g; j < LL; j += 8) {
        const float* vr = v + (size_t)(b * LL + j) * 256;
        #pragma unroll
        for (int h = 0; h < NH; ++h) acc[h] += lg[h][j] * vr[h * 32 + d];
    }
    #pragma unroll
    for (int h = 0; h < NH; ++h) part[g][h * 32 + d] = acc[h];
    __syncthreads();
    float sum = 0.f;
    #pragma unroll
    for (int g2 = 0; g2 < 8; ++g2) sum += part[g2][tid];
    outp[rowq + tid] = sum * invs[tid >> 5];
}

// ---------------- final frame update ---------------------------------------
__global__ __launch_bounds__(256) void k_final(
        const float* __restrict__ h, const float* __restrict__ out_w,
        const float* __restrict__ out_b, const float* __restrict__ rots,
        const float* __restrict__ trans, float* __restrict__ out) {
    __shared__ float w_s[256 * 6];
    for (int i = threadIdx.x; i < 1536; i += 256) w_s[i] = out_w[i];
    __syncthreads();
    int row = blockIdx.x * 256 + threadIdx.x;
    if (row >= BL) return;
    const float* hr = h + (size_t)row * 256;
    float corr[6];
    #pragma unroll
    for (int c = 0; c < 6; ++c) corr[c] = out_b[c];
    for (int k = 0; k < 256; ++k) {
        float hv = hr[k];
        #pragma unroll
        for (int c = 0; c < 6; ++c) corr[c] += hv * w_s[k * 6 + c];
    }
    float vx = corr[0], vy = corr[1], vz = corr[2];
    float n = sqrtf(vx * vx + vy * vy + vz * vz);
    float inv = 1.0f / (n + 1e-8f);
    float ax = vx * inv, ay = vy * inv, az = vz * inv;
    float s = sinf(n), cc = 1.0f - cosf(n);
    float K[9] = {0.f, -az, ay,  az, 0.f, -ax,  -ay, ax, 0.f};
    float K2[9];
    #pragma unroll
    for (int ii = 0; ii < 3; ++ii)
        #pragma unroll
        for (int jj = 0; jj < 3; ++jj)
            K2[ii * 3 + jj] = K[ii * 3 + 0] * K[0 * 3 + jj]
                            + K[ii * 3 + 1] * K[1 * 3 + jj]
                            + K[ii * 3 + 2] * K[2 * 3 + jj];
    float R[9];
    #pragma unroll
    for (int ii = 0; ii < 3; ++ii)
        #pragma unroll
        for (int jj = 0; jj < 3; ++jj)
            R[ii * 3 + jj] = (ii == jj ? 1.0f : 0.0f) + s * K[ii * 3 + jj] + cc * K2[ii * 3 + jj];
    const float* ro = rots + (size_t)row * 9;
    float* o = out + (size_t)row * 12;
    #pragma unroll
    for (int ii = 0; ii < 3; ++ii)
        #pragma unroll
        for (int jj = 0; jj < 3; ++jj)
            o[ii * 3 + jj] = ro[ii * 3 + 0] * R[0 * 3 + jj]
                           + ro[ii * 3 + 1] * R[1 * 3 + jj]
                           + ro[ii * 3 + 2] * R[2 * 3 + jj];
    float t0 = corr[3], t1 = corr[4], t2 = corr[5];
    const float* tr = trans + (size_t)row * 3;
    #pragma unroll
    for (int ii = 0; ii < 3; ++ii)
        o[9 + ii] = ro[ii * 3 + 0] * t0 + ro[ii * 3 + 1] * t1 + ro[ii * 3 + 2] * t2 + tr[ii];
}

extern "C" void kernel_launch(void* const* d_in, const int* in_sizes, int n_in,
                              void* d_out, int out_size, void* d_ws, size_t ws_size,
                              hipStream_t stream) {
    (void)in_sizes; (void)n_in; (void)out_size;
    const float* rots     = (const float*)d_in[0];
    const float* trans    = (const float*)d_in[1];
    const float* t        = (const float*)d_in[2];
    const float* single   = (const float*)d_in[3];
    const float* pair     = (const float*)d_in[4];
    const float* frame_w  = (const float*)d_in[5];
    const float* frame_b  = (const float*)d_in[6];
    const float* single_w = (const float*)d_in[7];
    const float* single_b = (const float*)d_in[8];
    const float* tw1      = (const float*)d_in[9];
    const float* tb1      = (const float*)d_in[10];
    const float* tw2      = (const float*)d_in[11];
    const float* tb2      = (const float*)d_in[12];
    const float* out_w    = (const float*)d_in[13];
    const float* out_b    = (const float*)d_in[14];
    const float* ag1      = (const float*)d_in[15];
    const float* abeta1   = (const float*)d_in[16];
    const float* apw1     = (const float*)d_in[17];
    const float* apb1     = (const float*)d_in[18];
    const float* wq       = (const float*)d_in[19];
    const float* wk       = (const float*)d_in[20];
    const float* wv       = (const float*)d_in[21];
    const float* pw       = (const float*)d_in[22];
    const float* wo       = (const float*)d_in[23];
    const float* wob      = (const float*)d_in[24];
    const float* ag2      = (const float*)d_in[25];
    const float* abeta2   = (const float*)d_in[26];
    const float* apw2     = (const float*)d_in[27];
    const float* apb2     = (const float*)d_in[28];
    const float* fw1      = (const float*)d_in[29];
    const float* fb1      = (const float*)d_in[30];
    const float* fw2      = (const float*)d_in[31];
    const float* fb2      = (const float*)d_in[32];

    float* ws = (float*)d_ws;
    float* time_cond = ws;                    // 512
    float* ss1 = time_cond + 512;             // 4096
    float* ss2 = ss1 + 4096;                  // 4096
    float* h   = ss2 + 4096;                  // 393216
    float* hh  = h + 393216;
    float* q   = hh + 393216;
    float* k_  = q + 393216;
    float* v   = k_ + 393216;
    float* attnout = v + 393216;
    float* mid = attnout + 393216;            // 1572864
    float* pb  = mid + 1572864;               // 37748736 floats (151 MB)

    const size_t base_floats = 3940864ull;
    const size_t need = (base_floats + 37748736ull) * 4ull;
    const bool big = ws_size >= need;

    k_time<<<BB, 256, 0, stream>>>(t, tw1, tb1, tw2, tb2, time_cond);
    k_ss<<<dim3(NBLK, BB, 2), 512, 0, stream>>>(time_cond, apw1, apb1, apw2, apb2, ss1, ss2);
    k_init_h<<<BL, 256, 0, stream>>>(rots, trans, single, frame_w, frame_b,
                                     single_w, single_b, h);
    if (big)
        k_pairbias<<<dim3(BL, 3), 256, 0, stream>>>(pair, pw, pb);

    for (int n = 0; n < NBLK; ++n) {
        k_adaln<<<BL, 256, 0, stream>>>(h, ag1 + n * 256, abeta1 + n * 256,
                                        ss1 + (size_t)n * BB * 512, hh);
        k_gemm_qkv<<<BL / 4, 256, 0, stream>>>(hh, wq + (size_t)n * 65536,
                                               wk + (size_t)n * 65536,
                                               wv + (size_t)n * 65536, q, k_, v);
        if (big)
            k_attn3<<<BB * NH * 48, 256, 0, stream>>>(q, k_, v, pb, n, attnout);
        else
            k_attn<<<BL, 256, 0, stream>>>(q, k_, v, pair, pw + n * 512, attnout);
        k_gemm4<1, 1><<<BL / 4, 256, 0, stream>>>(attnout, wo + (size_t)n * 65536,
                                                  wob + n * 256, h, h, 1 | 4);
        k_adaln<<<BL, 256, 0, stream>>>(h, ag2 + n * 256, abeta2 + n * 256,
                                        ss2 + (size_t)n * BB * 512, hh);
        k_gemm4<4, 1><<<BL / 4, 256, 0, stream>>>(hh, fw1 + (size_t)n * 262144,
                                                  fb1 + n * 1024, nullptr, mid, 1 | 2);
        k_gemm4<1, 4><<<BL / 4, 256, 0, stream>>>(mid, fw2 + (size_t)n * 262144,
                                                  fb2 + n * 256, h, h, 1 | 4);
    }
    k_final<<<6, 256, 0, stream>>>(h, out_w, out_b, rots, trans, (float*)d_out);
}

// Round 4
// 1272.754 us; speedup vs baseline: 2.6470x; 1.5356x over previous
//
#include <hip/hip_runtime.h>
#include <math.h>

#define BB 2
#define LL 768
#define CC 256
#define CZ 64
#define NH 8
#define NBLK 4
#define HD 32
#define BL (BB*LL)   // 1536

typedef unsigned short ushort_t;
typedef float f32x4 __attribute__((ext_vector_type(4)));
typedef __bf16 bf16x8 __attribute__((ext_vector_type(8)));

__device__ __forceinline__ float gelu_exact(float x) {
    return 0.5f * x * (1.0f + erff(x * 0.70710678118654752f));
}

__device__ __forceinline__ ushort_t f2bf(float f) {
    union { float f; unsigned u; } x; x.f = f;
    unsigned r = x.u + 0x7fffu + ((x.u >> 16) & 1u);
    return (ushort_t)(r >> 16);
}

// ---------------- time embedding + MLP -> time_cond (B,256) ----------------
__global__ __launch_bounds__(256) void k_time(
        const float* __restrict__ t,
        const float* __restrict__ tw1, const float* __restrict__ tb1,
        const float* __restrict__ tw2, const float* __restrict__ tb2,
        float* __restrict__ time_cond) {
    __shared__ float temb[256];
    __shared__ float mid[1024];
    int b = blockIdx.x;
    int tid = threadIdx.x;
    if (tid < 128) {
        float f = expf(-logf(10000.0f) * (float)tid / 128.0f);
        float a = t[b] * f;
        temb[tid]       = cosf(a);
        temb[128 + tid] = sinf(a);
    }
    __syncthreads();
    #pragma unroll
    for (int m = 0; m < 4; ++m) {
        int col = tid + 256 * m;
        float acc = tb1[col];
        #pragma unroll 8
        for (int k = 0; k < 256; ++k) acc += temb[k] * tw1[(size_t)k * 1024 + col];
        mid[col] = gelu_exact(acc);
    }
    __syncthreads();
    float acc = tb2[tid];
    #pragma unroll 8
    for (int k = 0; k < 1024; ++k) acc += mid[k] * tw2[(size_t)k * 256 + tid];
    time_cond[b * 256 + tid] = acc;
}

// ---------------- adaln scale/shift tables ---------------------------------
__global__ __launch_bounds__(512) void k_ss(
        const float* __restrict__ tc,
        const float* __restrict__ apw1, const float* __restrict__ apb1,
        const float* __restrict__ apw2, const float* __restrict__ apb2,
        float* __restrict__ ss1, float* __restrict__ ss2) {
    int n = blockIdx.x, b = blockIdx.y, which = blockIdx.z;
    const float* apw = which ? apw2 : apw1;
    const float* apb = which ? apb2 : apb1;
    float* ss = which ? ss2 : ss1;
    __shared__ float tcl[256];
    int tid = threadIdx.x;
    if (tid < 256) tcl[tid] = tc[b * 256 + tid];
    __syncthreads();
    float acc = apb[n * 512 + tid];
    const float* w = apw + (size_t)n * 256 * 512 + tid;
    #pragma unroll 8
    for (int k = 0; k < 256; ++k) acc += tcl[k] * w[(size_t)k * 512];
    ss[(size_t)(n * BB + b) * 512 + tid] = acc;
}

// ---------------- h init ----------------------------------------------------
__global__ __launch_bounds__(256) void k_init_h(
        const float* __restrict__ rots, const float* __restrict__ trans,
        const float* __restrict__ single,
        const float* __restrict__ frame_w, const float* __restrict__ frame_b,
        const float* __restrict__ single_w, const float* __restrict__ single_b,
        float* __restrict__ h) {
    int row = blockIdx.x;
    int tid = threadIdx.x;
    __shared__ float ff[12];
    __shared__ float sr[256];
    if (tid < 9) ff[tid] = rots[(size_t)row * 9 + tid];
    else if (tid < 12) ff[tid] = trans[(size_t)row * 3 + (tid - 9)];
    sr[tid] = single[(size_t)row * 256 + tid];
    __syncthreads();
    float acc = frame_b[tid] + single_b[tid];
    #pragma unroll
    for (int k = 0; k < 12; ++k) acc += ff[k] * frame_w[k * 256 + tid];
    #pragma unroll 8
    for (int k = 0; k < 256; ++k) acc += sr[k] * single_w[k * 256 + tid];
    h[(size_t)row * 256 + tid] = acc;
}

// ---------------- adaln layernorm (fp32 out — fallback path) ----------------
__global__ __launch_bounds__(256) void k_adaln(
        const float* __restrict__ h, const float* __restrict__ g,
        const float* __restrict__ beta, const float* __restrict__ ss,
        float* __restrict__ out) {
    int row = blockIdx.x;
    int b = row / LL;
    int tid = threadIdx.x;
    float x = h[(size_t)row * 256 + tid];
    float s = x, sq = x * x;
    #pragma unroll
    for (int off = 32; off > 0; off >>= 1) {
        s  += __shfl_down(s,  off, 64);
        sq += __shfl_down(sq, off, 64);
    }
    __shared__ float red[8];
    int wave = tid >> 6, lane = tid & 63;
    if (lane == 0) { red[wave] = s; red[4 + wave] = sq; }
    __syncthreads();
    if (tid == 0) {
        float ts = red[0] + red[1] + red[2] + red[3];
        float tq = red[4] + red[5] + red[6] + red[7];
        float mu = ts * (1.0f / 256.0f);
        float var = tq * (1.0f / 256.0f) - mu * mu;
        red[0] = mu;
        red[1] = rsqrtf(var + 1e-5f);
    }
    __syncthreads();
    float mu = red[0], inv = red[1];
    float ln = (x - mu) * inv * g[tid] + beta[tid];
    float scale = ss[b * 512 + tid];
    float shift = ss[b * 512 + 256 + tid];
    out[(size_t)row * 256 + tid] = ln * (1.0f + scale) + shift;
}

// ---------------- adaln layernorm, bf16 out ---------------------------------
__global__ __launch_bounds__(256) void k_adaln_bf(
        const float* __restrict__ h, const float* __restrict__ g,
        const float* __restrict__ beta, const float* __restrict__ ss,
        ushort_t* __restrict__ out) {
    int row = blockIdx.x;
    int b = row / LL;
    int tid = threadIdx.x;
    float x = h[(size_t)row * 256 + tid];
    float s = x, sq = x * x;
    #pragma unroll
    for (int off = 32; off > 0; off >>= 1) {
        s  += __shfl_down(s,  off, 64);
        sq += __shfl_down(sq, off, 64);
    }
    __shared__ float red[8];
    int wave = tid >> 6, lane = tid & 63;
    if (lane == 0) { red[wave] = s; red[4 + wave] = sq; }
    __syncthreads();
    if (tid == 0) {
        float ts = red[0] + red[1] + red[2] + red[3];
        float tq = red[4] + red[5] + red[6] + red[7];
        float mu = ts * (1.0f / 256.0f);
        float var = tq * (1.0f / 256.0f) - mu * mu;
        red[0] = mu;
        red[1] = rsqrtf(var + 1e-5f);
    }
    __syncthreads();
    float mu = red[0], inv = red[1];
    float ln = (x - mu) * inv * g[tid] + beta[tid];
    float scale = ss[b * 512 + tid];
    float shift = ss[b * 512 + 256 + tid];
    out[(size_t)row * 256 + tid] = f2bf(ln * (1.0f + scale) + shift);
}

// ---------------- weight convert + transpose to bf16 B^T layout -------------
// dst[n][k] = (bf16) src[k][n]
__global__ __launch_bounds__(256) void k_wt(
        const float* __restrict__ wq, const float* __restrict__ wk,
        const float* __restrict__ wv, const float* __restrict__ wo,
        const float* __restrict__ fw1, const float* __restrict__ fw2,
        ushort_t* __restrict__ wqkv_bt, ushort_t* __restrict__ wo_bt,
        ushort_t* __restrict__ fw1_bt, ushort_t* __restrict__ fw2_bt) {
    int type = blockIdx.z, nb = blockIdx.y, idx = blockIdx.x;
    int K, N; const float* src; ushort_t* dst;
    switch (type) {
        case 0: K = 256; N = 256;  src = wq  + (size_t)nb * 65536;  dst = wqkv_bt + (size_t)nb * 196608;           break;
        case 1: K = 256; N = 256;  src = wk  + (size_t)nb * 65536;  dst = wqkv_bt + (size_t)nb * 196608 + 65536;   break;
        case 2: K = 256; N = 256;  src = wv  + (size_t)nb * 65536;  dst = wqkv_bt + (size_t)nb * 196608 + 131072;  break;
        case 3: K = 256; N = 256;  src = wo  + (size_t)nb * 65536;  dst = wo_bt  + (size_t)nb * 65536;             break;
        case 4: K = 256; N = 1024; src = fw1 + (size_t)nb * 262144; dst = fw1_bt + (size_t)nb * 262144;            break;
        default:K = 1024; N = 256; src = fw2 + (size_t)nb * 262144; dst = fw2_bt + (size_t)nb * 262144;            break;
    }
    int tilesN = N >> 6;
    int tiles = (K >> 6) * tilesN;
    if (idx >= tiles) return;
    int k0 = (idx / tilesN) * 64, n0 = (idx % tilesN) * 64;
    __shared__ float lds[64][65];
    int tn = threadIdx.x & 63, tk = threadIdx.x >> 6;
    #pragma unroll
    for (int r = 0; r < 16; ++r) {
        int kk = tk + 4 * r;
        lds[kk][tn] = src[(size_t)(k0 + kk) * N + n0 + tn];
    }
    __syncthreads();
    #pragma unroll
    for (int r = 0; r < 16; ++r) {
        int nn = tk + 4 * r;
        dst[(size_t)(n0 + nn) * K + k0 + tn] = f2bf(lds[tn][nn]);
    }
}

// ---------------- MFMA bf16 GEMM: 64x64 block tile, 4 waves -----------------
// C[m][n] = sum_k A[m][k] * Wt[n][k].  A bf16 [M][K], Wt bf16 [N][K].
// MODE 0: write fp32 q/k/v split by n/256 (N=768, no bias)
// MODE 1: + bias + resid -> fp32 out (N=256)
// MODE 2: + bias, gelu -> bf16 out (N=1024)
template<int KSTEPS, int MODE>
__global__ __launch_bounds__(256) void k_mfma(
        const ushort_t* __restrict__ A, const ushort_t* __restrict__ Wt,
        const float* __restrict__ bias, const float* __restrict__ resid,
        float* __restrict__ outf, ushort_t* __restrict__ outb,
        float* __restrict__ qo, float* __restrict__ ko, float* __restrict__ vo) {
    const int K = KSTEPS * 32;
    int m0 = blockIdx.x * 64, n0 = blockIdx.y * 64;
    int t = threadIdx.x;
    int wave = t >> 6, lane = t & 63, quad = lane >> 4, l16 = lane & 15;
    const bf16x8* Ap = (const bf16x8*)(A + (size_t)(m0 + wave * 16 + l16) * K + quad * 8);
    const bf16x8* Wp = (const bf16x8*)(Wt + (size_t)(n0 + l16) * K + quad * 8);
    const int wstride = 2 * K;  // 16 rows of Wt in bf16x8 units
    f32x4 acc[4];
    #pragma unroll
    for (int nt = 0; nt < 4; ++nt) acc[nt] = f32x4{0.f, 0.f, 0.f, 0.f};

    #pragma unroll
    for (int ks = 0; ks < KSTEPS; ++ks) {
        bf16x8 av = Ap[ks * 4];
        #pragma unroll
        for (int nt = 0; nt < 4; ++nt) {
            bf16x8 bv = Wp[nt * wstride + ks * 4];
            acc[nt] = __builtin_amdgcn_mfma_f32_16x16x32_bf16(av, bv, acc[nt], 0, 0, 0);
        }
    }

    int row_base = m0 + wave * 16 + quad * 4;
    #pragma unroll
    for (int nt = 0; nt < 4; ++nt) {
        int n = n0 + nt * 16 + l16;
        #pragma unroll
        for (int r = 0; r < 4; ++r) {
            int row = row_base + r;
            float val = acc[nt][r];
            if (MODE == 0) {
                float* dst = (n < 256) ? qo : ((n < 512) ? ko : vo);
                dst[(size_t)row * 256 + (n & 255)] = val;
            } else if (MODE == 1) {
                val += bias[n] + resid[(size_t)row * 256 + n];
                outf[(size_t)row * 256 + n] = val;
            } else {
                val = gelu_exact(val + bias[n]);
                outb[(size_t)row * 1024 + n] = f2bf(val);
            }
        }
    }
}

// ---------------- generic tiled GEMM (fallback path) ------------------------
template<int NCOL, int KCH>
__global__ __launch_bounds__(256) void k_gemm4(
        const float* __restrict__ A, const float* __restrict__ W,
        const float* __restrict__ bias, const float* __restrict__ resid,
        float* __restrict__ out, int flags) {
    const int N = 256 * NCOL;
    const int K = 256 * KCH;
    int row0 = blockIdx.x * 4;
    int tid = threadIdx.x;
    __shared__ float a_s[4][256];
    float acc[4][NCOL];
    #pragma unroll
    for (int r = 0; r < 4; ++r)
        #pragma unroll
        for (int m = 0; m < NCOL; ++m) acc[r][m] = 0.f;

    for (int kc = 0; kc < KCH; ++kc) {
        if (kc) __syncthreads();
        {
            int r = tid >> 6, c4 = tid & 63;
            float4 av = reinterpret_cast<const float4*>(
                A + (size_t)(row0 + r) * K + kc * 256)[c4];
            *reinterpret_cast<float4*>(&a_s[r][c4 * 4]) = av;
        }
        __syncthreads();
        const float* Wp = W + (size_t)kc * 256 * N + tid;
        #pragma unroll 4
        for (int k = 0; k < 256; ++k) {
            float bv[NCOL];
            #pragma unroll
            for (int m = 0; m < NCOL; ++m) bv[m] = Wp[(size_t)k * N + 256 * m];
            #pragma unroll
            for (int r = 0; r < 4; ++r) {
                float a = a_s[r][k];
                #pragma unroll
                for (int m = 0; m < NCOL; ++m) acc[r][m] += a * bv[m];
            }
        }
    }
    #pragma unroll
    for (int r = 0; r < 4; ++r) {
        int row = row0 + r;
        #pragma unroll
        for (int m = 0; m < NCOL; ++m) {
            int col = tid + 256 * m;
            float v = acc[r][m];
            if (flags & 1) v += bias[col];
            if (flags & 2) v = gelu_exact(v);
            if (flags & 4) v += resid[(size_t)row * N + col];
            out[(size_t)row * N + col] = v;
        }
    }
}

// ---------------- fused QKV GEMM (fallback) ---------------------------------
__global__ __launch_bounds__(256) void k_gemm_qkv(
        const float* __restrict__ A,
        const float* __restrict__ Wq, const float* __restrict__ Wk,
        const float* __restrict__ Wv,
        float* __restrict__ q, float* __restrict__ k_,
        float* __restrict__ v) {
    int row0 = blockIdx.x * 4;
    int tid = threadIdx.x;
    __shared__ float a_s[4][256];
    {
        int r = tid >> 6, c4 = tid & 63;
        float4 av = reinterpret_cast<const float4*>(
            A + (size_t)(row0 + r) * 256)[c4];
        *reinterpret_cast<float4*>(&a_s[r][c4 * 4]) = av;
    }
    __syncthreads();
    float aq[4] = {0,0,0,0}, ak[4] = {0,0,0,0}, av_[4] = {0,0,0,0};
    #pragma unroll 4
    for (int k = 0; k < 256; ++k) {
        float wq_ = Wq[(size_t)k * 256 + tid];
        float wk_ = Wk[(size_t)k * 256 + tid];
        float wv_ = Wv[(size_t)k * 256 + tid];
        #pragma unroll
        for (int r = 0; r < 4; ++r) {
            float a = a_s[r][k];
            aq[r]  += a * wq_;
            ak[r]  += a * wk_;
            av_[r] += a * wv_;
        }
    }
    #pragma unroll
    for (int r = 0; r < 4; ++r) {
        size_t o = (size_t)(row0 + r) * 256 + tid;
        q[o] = aq[r]; k_[o] = ak[r]; v[o] = av_[r];
    }
}

// ---------------- pair bias precompute: pb[b][n*8+h][i][j] ------------------
__global__ __launch_bounds__(256) void k_pairbias(
        const float* __restrict__ pair, const float* __restrict__ pw,
        float* __restrict__ pb) {
    int row = blockIdx.x;            // b*768 + i
    int b = row / LL, i = row % LL;
    int tid = threadIdx.x;
    int j = blockIdx.y * 256 + tid;
    __shared__ float pw_t[2048];     // [nh][c] transposed
    #pragma unroll
    for (int x = 0; x < 8; ++x) {
        int idx = tid + 256 * x;
        int nh = idx >> 6, c = idx & 63;
        pw_t[idx] = pw[(nh >> 3) * 512 + c * 8 + (nh & 7)];
    }
    __syncthreads();
    float pr[64];
    {
        const float4* p4 = reinterpret_cast<const float4*>(
            pair + ((size_t)row * LL + j) * CZ);
        #pragma unroll
        for (int x = 0; x < 16; ++x) {
            float4 t4 = p4[x];
            pr[4*x] = t4.x; pr[4*x+1] = t4.y; pr[4*x+2] = t4.z; pr[4*x+3] = t4.w;
        }
    }
    #pragma unroll 4
    for (int nh = 0; nh < 32; ++nh) {
        const float4* wr = reinterpret_cast<const float4*>(&pw_t[nh * 64]);
        float s0 = 0.f, s1 = 0.f, s2 = 0.f, s3 = 0.f;
        #pragma unroll
        for (int c4 = 0; c4 < 16; ++c4) {
            float4 wv = wr[c4];
            s0 += pr[4*c4]   * wv.x;
            s1 += pr[4*c4+1] * wv.y;
            s2 += pr[4*c4+2] * wv.z;
            s3 += pr[4*c4+3] * wv.w;
        }
        pb[(((size_t)(b * 32 + nh)) * LL + i) * LL + j] = (s0 + s1) + (s2 + s3);
    }
}

// ---------------- attention v3: register logits, bf16 out -------------------
// grid: b(2) x h(8) x it(48) = 768 blocks, 256 threads.
__global__ __launch_bounds__(256) void k_attn3(
        const float* __restrict__ q, const float* __restrict__ kk,
        const float* __restrict__ v, const float* __restrict__ pb,
        int n, ushort_t* __restrict__ outp) {
    int blk = blockIdx.x;
    int it = blk % 48;
    int bh = blk / 48;
    int h = bh % NH;
    int b = bh / NH;
    int i0 = it * 16;
    int t = threadIdx.x;
    int i = t & 15;
    int jg = t >> 4;
    int wave = t >> 6, lane = t & 63;

    __shared__ float q_s[16][36];      // stride 36: 16B-aligned, 2-way banks
    __shared__ float red_m[4][16];
    __shared__ float red_l[4][16];
    __shared__ float linv[16];
    __shared__ float part[4][16][36];  // stride 36

    if (t < 128) {
        int qi = t >> 3, x = t & 7;
        reinterpret_cast<float4*>(&q_s[qi][x * 4])[0] =
            reinterpret_cast<const float4*>(
                q + ((size_t)(b * LL + i0 + qi)) * 256 + h * 32)[x];
    }
    __syncthreads();

    float qr[32];
    #pragma unroll
    for (int x = 0; x < 8; ++x) {
        float4 t4 = reinterpret_cast<const float4*>(&q_s[i][0])[x];
        qr[4*x] = t4.x; qr[4*x+1] = t4.y; qr[4*x+2] = t4.z; qr[4*x+3] = t4.w;
    }

    const float* pbrow = pb + (((size_t)(b * 32 + n * NH + h)) * LL + (i0 + i)) * LL + jg * 48;
    const float* Kbase = kk + ((size_t)(b * LL + jg * 48)) * 256 + h * 32;
    const float* Vbase = v  + ((size_t)(b * LL + jg * 48)) * 256 + h * 32;
    const float scale = 0.17677669529663687f; // 1/sqrt(32)

    float lg[48];
    #pragma unroll
    for (int jj = 0; jj < 48; ++jj) {
        const float4* kr = reinterpret_cast<const float4*>(Kbase + (size_t)jj * 256);
        float a0 = 0.f, a1 = 0.f, a2 = 0.f, a3 = 0.f;
        #pragma unroll
        for (int x = 0; x < 8; ++x) {
            float4 kv = kr[x];
            a0 += qr[4*x]   * kv.x;
            a1 += qr[4*x+1] * kv.y;
            a2 += qr[4*x+2] * kv.z;
            a3 += qr[4*x+3] * kv.w;
        }
        lg[jj] = ((a0 + a1) + (a2 + a3)) * scale;
    }
    #pragma unroll
    for (int x = 0; x < 12; ++x) {
        float4 bv = reinterpret_cast<const float4*>(pbrow)[x];
        lg[4*x]   += bv.x; lg[4*x+1] += bv.y;
        lg[4*x+2] += bv.z; lg[4*x+3] += bv.w;
    }

    float m = -1e30f;
    #pragma unroll
    for (int jj = 0; jj < 48; ++jj) m = fmaxf(m, lg[jj]);
    m = fmaxf(m, __shfl_xor(m, 16, 64));
    m = fmaxf(m, __shfl_xor(m, 32, 64));
    if (lane < 16) red_m[wave][lane] = m;
    __syncthreads();
    m = fmaxf(fmaxf(red_m[0][i], red_m[1][i]), fmaxf(red_m[2][i], red_m[3][i]));

    float l = 0.f;
    #pragma unroll
    for (int jj = 0; jj < 48; ++jj) {
        float e = __expf(lg[jj] - m);
        lg[jj] = e;
        l += e;
    }
    l += __shfl_xor(l, 16, 64);
    l += __shfl_xor(l, 32, 64);
    if (lane < 16) red_l[wave][lane] = l;
    __syncthreads();
    if (t < 16) linv[t] = 1.0f / ((red_l[0][t] + red_l[1][t]) + (red_l[2][t] + red_l[3][t]));

    float O[32];
    #pragma unroll
    for (int x = 0; x < 32; ++x) O[x] = 0.f;
    #pragma unroll
    for (int jj = 0; jj < 48; ++jj) {
        float e = lg[jj];
        const float4* vr = reinterpret_cast<const float4*>(Vbase + (size_t)jj * 256);
        #pragma unroll
        for (int x = 0; x < 8; ++x) {
            float4 vv = vr[x];
            O[4*x]   += e * vv.x;
            O[4*x+1] += e * vv.y;
            O[4*x+2] += e * vv.z;
            O[4*x+3] += e * vv.w;
        }
    }
    #pragma unroll
    for (int x = 0; x < 32; ++x) {
        O[x] += __shfl_xor(O[x], 16, 64);
        O[x] += __shfl_xor(O[x], 32, 64);
    }
    if (lane < 16) {
        #pragma unroll
        for (int x = 0; x < 8; ++x) {
            float4 o4 = make_float4(O[4*x], O[4*x+1], O[4*x+2], O[4*x+3]);
            reinterpret_cast<float4*>(&part[wave][lane][4*x])[0] = o4;
        }
    }
    __syncthreads();
    #pragma unroll
    for (int o = 0; o < 2; ++o) {
        int idx = t + o * 256;
        int oi = idx >> 5, od = idx & 31;
        float s = (part[0][oi][od] + part[1][oi][od])
                + (part[2][oi][od] + part[3][oi][od]);
        outp[((size_t)(b * LL + i0 + oi)) * 256 + h * 32 + od] = f2bf(s * linv[oi]);
    }
}

// ---------------- fallback fused attention (fp32 out) -----------------------
__global__ __launch_bounds__(256) void k_attn(
        const float* __restrict__ q, const float* __restrict__ kk,
        const float* __restrict__ v, const float* __restrict__ pair,
        const float* __restrict__ pw, float* __restrict__ outp) {
    int blk = blockIdx.x;
    int b = blk / LL, i = blk % LL;
    int tid = threadIdx.x;
    __shared__ float q_s[256];
    __shared__ float pw_s[CZ * NH];
    __shared__ float lg[NH][LL];
    __shared__ float part[8][256];
    __shared__ float invs[NH];
    size_t rowq = (size_t)(b * LL + i) * 256;
    q_s[tid] = q[rowq + tid];
    pw_s[tid] = pw[tid];
    pw_s[tid + 256] = pw[tid + 256];
    __syncthreads();

    const float scale = 0.17677669529663687f;
    for (int j = tid; j < LL; j += 256) {
        const float4* k4 = reinterpret_cast<const float4*>(kk + (size_t)(b * LL + j) * 256);
        const float4* q4 = reinterpret_cast<const float4*>(q_s);
        float dot[NH];
        #pragma unroll
        for (int h = 0; h < NH; ++h) {
            float sx = 0.f, sy = 0.f, sz = 0.f, sw = 0.f;
            #pragma unroll
            for (int dd = 0; dd < 8; ++dd) {
                float4 kv = k4[h * 8 + dd];
                float4 qv = q4[h * 8 + dd];
                sx += qv.x * kv.x; sy += qv.y * kv.y;
                sz += qv.z * kv.z; sw += qv.w * kv.w;
            }
            dot[h] = (sx + sy) + (sz + sw);
        }
        const float4* p4 = reinterpret_cast<const float4*>(
            pair + ((size_t)(b * LL + i) * LL + j) * CZ);
        float bias[NH];
        #pragma unroll
        for (int h = 0; h < NH; ++h) bias[h] = 0.f;
        #pragma unroll
        for (int c4 = 0; c4 < 16; ++c4) {
            float4 pv = p4[c4];
            int c = c4 * 4;
            #pragma unroll
            for (int h = 0; h < NH; ++h)
                bias[h] += pv.x * pw_s[(c + 0) * NH + h] + pv.y * pw_s[(c + 1) * NH + h]
                         + pv.z * pw_s[(c + 2) * NH + h] + pv.w * pw_s[(c + 3) * NH + h];
        }
        #pragma unroll
        for (int h = 0; h < NH; ++h) lg[h][j] = dot[h] * scale + bias[h];
    }
    __syncthreads();

    int wave = tid >> 6, lane = tid & 63;
    for (int h = wave; h < NH; h += 4) {
        float mx = -1e30f;
        for (int j = lane; j < LL; j += 64) mx = fmaxf(mx, lg[h][j]);
        #pragma unroll
        for (int off = 32; off > 0; off >>= 1) mx = fmaxf(mx, __shfl_xor(mx, off, 64));
        float sm = 0.f;
        for (int j = lane; j < LL; j += 64) {
            float e = __expf(lg[h][j] - mx);
            lg[h][j] = e;
            sm += e;
        }
        #pragma unroll
        for (int off = 32; off > 0; off >>= 1) sm += __shfl_xor(sm, off, 64);
        if (lane == 0) invs[h] = 1.0f / sm;
    }
    __syncthreads();

    int g = tid >> 5, d = tid & 31;
    float acc[NH];
    #pragma unroll
    for (int h = 0; h < NH; ++h) acc[h] = 0.f;
    for (int j = g; j < LL; j += 8) {
        const float* vr = v + (size_t)(b * LL + j) * 256;
        #pragma unroll
        for (int h = 0; h < NH; ++h) acc[h] += lg[h][j] * vr[h * 32 + d];
    }
    #pragma unroll
    for (int h = 0; h < NH; ++h) part[g][h * 32 + d] = acc[h];
    __syncthreads();
    float sum = 0.f;
    #pragma unroll
    for (int g2 = 0; g2 < 8; ++g2) sum += part[g2][tid];
    outp[rowq + tid] = sum * invs[tid >> 5];
}

// ---------------- final frame update ---------------------------------------
__global__ __launch_bounds__(256) void k_final(
        const float* __restrict__ h, const float* __restrict__ out_w,
        const float* __restrict__ out_b, const float* __restrict__ rots,
        const float* __restrict__ trans, float* __restrict__ out) {
    __shared__ float w_s[256 * 6];
    for (int i = threadIdx.x; i < 1536; i += 256) w_s[i] = out_w[i];
    __syncthreads();
    int row = blockIdx.x * 256 + threadIdx.x;
    if (row >= BL) return;
    const float* hr = h + (size_t)row * 256;
    float corr[6];
    #pragma unroll
    for (int c = 0; c < 6; ++c) corr[c] = out_b[c];
    for (int k = 0; k < 256; ++k) {
        float hv = hr[k];
        #pragma unroll
        for (int c = 0; c < 6; ++c) corr[c] += hv * w_s[k * 6 + c];
    }
    float vx = corr[0], vy = corr[1], vz = corr[2];
    float n = sqrtf(vx * vx + vy * vy + vz * vz);
    float inv = 1.0f / (n + 1e-8f);
    float ax = vx * inv, ay = vy * inv, az = vz * inv;
    float s = sinf(n), cc = 1.0f - cosf(n);
    float K[9] = {0.f, -az, ay,  az, 0.f, -ax,  -ay, ax, 0.f};
    float K2[9];
    #pragma unroll
    for (int ii = 0; ii < 3; ++ii)
        #pragma unroll
        for (int jj = 0; jj < 3; ++jj)
            K2[ii * 3 + jj] = K[ii * 3 + 0] * K[0 * 3 + jj]
                            + K[ii * 3 + 1] * K[1 * 3 + jj]
                            + K[ii * 3 + 2] * K[2 * 3 + jj];
    float R[9];
    #pragma unroll
    for (int ii = 0; ii < 3; ++ii)
        #pragma unroll
        for (int jj = 0; jj < 3; ++jj)
            R[ii * 3 + jj] = (ii == jj ? 1.0f : 0.0f) + s * K[ii * 3 + jj] + cc * K2[ii * 3 + jj];
    const float* ro = rots + (size_t)row * 9;
    float* o = out + (size_t)row * 12;
    #pragma unroll
    for (int ii = 0; ii < 3; ++ii)
        #pragma unroll
        for (int jj = 0; jj < 3; ++jj)
            o[ii * 3 + jj] = ro[ii * 3 + 0] * R[0 * 3 + jj]
                           + ro[ii * 3 + 1] * R[1 * 3 + jj]
                           + ro[ii * 3 + 2] * R[2 * 3 + jj];
    float t0 = corr[3], t1 = corr[4], t2 = corr[5];
    const float* tr = trans + (size_t)row * 3;
    #pragma unroll
    for (int ii = 0; ii < 3; ++ii)
        o[9 + ii] = ro[ii * 3 + 0] * t0 + ro[ii * 3 + 1] * t1 + ro[ii * 3 + 2] * t2 + tr[ii];
}

extern "C" void kernel_launch(void* const* d_in, const int* in_sizes, int n_in,
                              void* d_out, int out_size, void* d_ws, size_t ws_size,
                              hipStream_t stream) {
    (void)in_sizes; (void)n_in; (void)out_size;
    const float* rots     = (const float*)d_in[0];
    const float* trans    = (const float*)d_in[1];
    const float* t        = (const float*)d_in[2];
    const float* single   = (const float*)d_in[3];
    const float* pair     = (const float*)d_in[4];
    const float* frame_w  = (const float*)d_in[5];
    const float* frame_b  = (const float*)d_in[6];
    const float* single_w = (const float*)d_in[7];
    const float* single_b = (const float*)d_in[8];
    const float* tw1      = (const float*)d_in[9];
    const float* tb1      = (const float*)d_in[10];
    const float* tw2      = (const float*)d_in[11];
    const float* tb2      = (const float*)d_in[12];
    const float* out_w    = (const float*)d_in[13];
    const float* out_b    = (const float*)d_in[14];
    const float* ag1      = (const float*)d_in[15];
    const float* abeta1   = (const float*)d_in[16];
    const float* apw1     = (const float*)d_in[17];
    const float* apb1     = (const float*)d_in[18];
    const float* wq       = (const float*)d_in[19];
    const float* wk       = (const float*)d_in[20];
    const float* wv       = (const float*)d_in[21];
    const float* pw       = (const float*)d_in[22];
    const float* wo       = (const float*)d_in[23];
    const float* wob      = (const float*)d_in[24];
    const float* ag2      = (const float*)d_in[25];
    const float* abeta2   = (const float*)d_in[26];
    const float* apw2     = (const float*)d_in[27];
    const float* apb2     = (const float*)d_in[28];
    const float* fw1      = (const float*)d_in[29];
    const float* fb1      = (const float*)d_in[30];
    const float* fw2      = (const float*)d_in[31];
    const float* fb2      = (const float*)d_in[32];

    float* ws = (float*)d_ws;
    float* time_cond = ws;                    // 512
    float* ss1 = time_cond + 512;             // 4096
    float* ss2 = ss1 + 4096;                  // 4096
    float* h   = ss2 + 4096;                  // 393216
    float* hh  = h + 393216;                  // (fallback only)
    float* q   = hh + 393216;
    float* k_  = q + 393216;
    float* v   = k_ + 393216;
    float* attnout = v + 393216;              // (fallback only)
    float* mid = attnout + 393216;            // 1572864 (fallback only)
    float* pb  = mid + 1572864;               // 37748736 floats (151 MB)

    const size_t base_floats = 3940864ull;
    const size_t pb_floats = 37748736ull;
    ushort_t* us = (ushort_t*)(ws + base_floats + pb_floats);
    ushort_t* hh_bf      = us;                 // 393216
    ushort_t* attnout_bf = hh_bf + 393216;     // 393216
    ushort_t* mid_bf     = attnout_bf + 393216;// 1572864
    ushort_t* wqkv_bt    = mid_bf + 1572864;   // 786432
    ushort_t* wo_bt      = wqkv_bt + 786432;   // 262144
    ushort_t* fw1_bt     = wo_bt + 262144;     // 1048576
    ushort_t* fw2_bt     = fw1_bt + 1048576;   // 1048576
    const size_t us_count = 5505024ull;

    const size_t need = (base_floats + pb_floats) * 4ull + us_count * 2ull;
    const bool big = ws_size >= need;

    k_time<<<BB, 256, 0, stream>>>(t, tw1, tb1, tw2, tb2, time_cond);
    k_ss<<<dim3(NBLK, BB, 2), 512, 0, stream>>>(time_cond, apw1, apb1, apw2, apb2, ss1, ss2);
    k_init_h<<<BL, 256, 0, stream>>>(rots, trans, single, frame_w, frame_b,
                                     single_w, single_b, h);
    if (big) {
        k_wt<<<dim3(64, NBLK, 6), 256, 0, stream>>>(wq, wk, wv, wo, fw1, fw2,
                                                    wqkv_bt, wo_bt, fw1_bt, fw2_bt);
        k_pairbias<<<dim3(BL, 3), 256, 0, stream>>>(pair, pw, pb);
        for (int n = 0; n < NBLK; ++n) {
            k_adaln_bf<<<BL, 256, 0, stream>>>(h, ag1 + n * 256, abeta1 + n * 256,
                                               ss1 + (size_t)n * BB * 512, hh_bf);
            k_mfma<8, 0><<<dim3(24, 12), 256, 0, stream>>>(
                hh_bf, wqkv_bt + (size_t)n * 196608, nullptr, nullptr,
                nullptr, nullptr, q, k_, v);
            k_attn3<<<BB * NH * 48, 256, 0, stream>>>(q, k_, v, pb, n, attnout_bf);
            k_mfma<8, 1><<<dim3(24, 4), 256, 0, stream>>>(
                attnout_bf, wo_bt + (size_t)n * 65536, wob + n * 256, h,
                h, nullptr, nullptr, nullptr, nullptr);
            k_adaln_bf<<<BL, 256, 0, stream>>>(h, ag2 + n * 256, abeta2 + n * 256,
                                               ss2 + (size_t)n * BB * 512, hh_bf);
            k_mfma<8, 2><<<dim3(24, 16), 256, 0, stream>>>(
                hh_bf, fw1_bt + (size_t)n * 262144, fb1 + n * 1024, nullptr,
                nullptr, mid_bf, nullptr, nullptr, nullptr);
            k_mfma<32, 1><<<dim3(24, 4), 256, 0, stream>>>(
                mid_bf, fw2_bt + (size_t)n * 262144, fb2 + n * 256, h,
                h, nullptr, nullptr, nullptr, nullptr);
        }
    } else {
        for (int n = 0; n < NBLK; ++n) {
            k_adaln<<<BL, 256, 0, stream>>>(h, ag1 + n * 256, abeta1 + n * 256,
                                            ss1 + (size_t)n * BB * 512, hh);
            k_gemm_qkv<<<BL / 4, 256, 0, stream>>>(hh, wq + (size_t)n * 65536,
                                                   wk + (size_t)n * 65536,
                                                   wv + (size_t)n * 65536, q, k_, v);
            k_attn<<<BL, 256, 0, stream>>>(q, k_, v, pair, pw + n * 512, attnout);
            k_gemm4<1, 1><<<BL / 4, 256, 0, stream>>>(attnout, wo + (size_t)n * 65536,
                                                      wob + n * 256, h, h, 1 | 4);
            k_adaln<<<BL, 256, 0, stream>>>(h, ag2 + n * 256, abeta2 + n * 256,
                                            ss2 + (size_t)n * BB * 512, hh);
            k_gemm4<4, 1><<<BL / 4, 256, 0, stream>>>(hh, fw1 + (size_t)n * 262144,
                                                      fb1 + n * 1024, nullptr, mid, 1 | 2);
            k_gemm4<1, 4><<<BL / 4, 256, 0, stream>>>(mid, fw2 + (size_t)n * 262144,
                                                      fb2 + n * 256, h, h, 1 | 4);
        }
    }
    k_final<<<6, 256, 0, stream>>>(h, out_w, out_b, rots, trans, (float*)d_out);
}